// Round 1
// baseline (1381.294 us; speedup 1.0000x reference)
//
#include <hip/hip_runtime.h>
#include <math.h>

#define N_NODES 50000
#define N_EDGES 300000
#define BN_EPS 1e-5f
#define NEG_SLOPE 0.2f

// ---------------- BN0 (5 columns) ----------------
__global__ void bn0_stats(const float* __restrict__ h, const float* __restrict__ g,
                          const float* __restrict__ b, float* __restrict__ ss /*[10]: scale,shift*/) {
    __shared__ float s_sum[5], s_sq[5];
    int tid = threadIdx.x;
    if (tid < 5) { s_sum[tid] = 0.f; s_sq[tid] = 0.f; }
    __syncthreads();
    float ls[5] = {0,0,0,0,0}, lq[5] = {0,0,0,0,0};
    for (int r = tid; r < N_NODES; r += blockDim.x) {
        #pragma unroll
        for (int k = 0; k < 5; k++) {
            float v = h[r*5 + k];
            ls[k] += v; lq[k] += v*v;
        }
    }
    #pragma unroll
    for (int k = 0; k < 5; k++) { atomicAdd(&s_sum[k], ls[k]); atomicAdd(&s_sq[k], lq[k]); }
    __syncthreads();
    if (tid < 5) {
        float mean = s_sum[tid] * (1.f / N_NODES);
        float var  = s_sq[tid] * (1.f / N_NODES) - mean*mean;
        float sc = g[tid] * rsqrtf(var + BN_EPS);
        ss[tid]     = sc;
        ss[5 + tid] = b[tid] - mean * sc;
    }
}

__global__ void bn0_apply(const float* __restrict__ h, const float* __restrict__ ss,
                          float* __restrict__ x0) {
    int i = blockIdx.x * blockDim.x + threadIdx.x;
    if (i < N_NODES * 5) {
        int k = i % 5;
        x0[i] = h[i] * ss[k] + ss[5 + k];
    }
}

// ---------------- CSR build by dst ----------------
__global__ void edge_count(const int* __restrict__ dst, int* __restrict__ count) {
    int e = blockIdx.x * blockDim.x + threadIdx.x;
    if (e < N_EDGES) atomicAdd(&count[dst[e]], 1);
}

__global__ void scan_offsets(const int* __restrict__ count, int* __restrict__ offsets,
                             int* __restrict__ cursor) {
    __shared__ int lds[1024];
    __shared__ int carry;
    int tid = threadIdx.x;
    if (tid == 0) carry = 0;
    __syncthreads();
    for (int base = 0; base < N_NODES; base += 1024) {
        int v = (base + tid < N_NODES) ? count[base + tid] : 0;
        lds[tid] = v;
        __syncthreads();
        for (int off = 1; off < 1024; off <<= 1) {
            int t = (tid >= off) ? lds[tid - off] : 0;
            __syncthreads();
            lds[tid] += t;
            __syncthreads();
        }
        int excl = carry + lds[tid] - v;
        if (base + tid < N_NODES) { offsets[base + tid] = excl; cursor[base + tid] = excl; }
        __syncthreads();
        if (tid == 0) carry += lds[1023];
        __syncthreads();
    }
    if (tid == 0) offsets[N_NODES] = carry;
}

__global__ void edge_scatter(const int* __restrict__ dst, int* __restrict__ cursor,
                             int* __restrict__ perm) {
    int e = blockIdx.x * blockDim.x + threadIdx.x;
    if (e < N_EDGES) {
        int pos = atomicAdd(&cursor[dst[e]], 1);
        perm[pos] = e;
    }
}

// ---------------- conv1 linear (K=5) ----------------
__global__ void gemm_k5(const float* __restrict__ x0,
                        const float* __restrict__ Wl, const float* __restrict__ bl,
                        const float* __restrict__ Wr, const float* __restrict__ br,
                        float* __restrict__ xl, float* __restrict__ xr) {
    int n = blockIdx.x;
    int c = threadIdx.x;
    float a0 = x0[n*5+0], a1 = x0[n*5+1], a2 = x0[n*5+2], a3 = x0[n*5+3], a4 = x0[n*5+4];
    float l = bl[c] + a0*Wl[c] + a1*Wl[256+c] + a2*Wl[512+c] + a3*Wl[768+c] + a4*Wl[1024+c];
    float r = br[c] + a0*Wr[c] + a1*Wr[256+c] + a2*Wr[512+c] + a3*Wr[768+c] + a4*Wr[1024+c];
    xl[n*256 + c] = l;
    xr[n*256 + c] = r;
}

// ---------------- big linear (K=256), computes both Wl and Wr products ----------------
__global__ __launch_bounds__(256) void gemm_k256(const float* __restrict__ x,
                        const float* __restrict__ Wl, const float* __restrict__ bl,
                        const float* __restrict__ Wr, const float* __restrict__ br,
                        float* __restrict__ xl, float* __restrict__ xr) {
    __shared__ float As[16 * 256];
    int n0 = blockIdx.x * 16;
    int tid = threadIdx.x;
    #pragma unroll
    for (int it = 0; it < 16; it++) {
        int idx = it * 256 + tid;
        As[idx] = x[n0 * 256 + idx];
    }
    __syncthreads();
    int c = tid;
    float accl[16], accr[16];
    #pragma unroll
    for (int r = 0; r < 16; r++) { accl[r] = 0.f; accr[r] = 0.f; }
    for (int k = 0; k < 256; k += 4) {
        float wl0 = Wl[(k+0)*256 + c], wl1 = Wl[(k+1)*256 + c];
        float wl2 = Wl[(k+2)*256 + c], wl3 = Wl[(k+3)*256 + c];
        float wr0 = Wr[(k+0)*256 + c], wr1 = Wr[(k+1)*256 + c];
        float wr2 = Wr[(k+2)*256 + c], wr3 = Wr[(k+3)*256 + c];
        #pragma unroll
        for (int r = 0; r < 16; r++) {
            float4 a = *(const float4*)(&As[r*256 + k]);
            accl[r] += a.x*wl0 + a.y*wl1 + a.z*wl2 + a.w*wl3;
            accr[r] += a.x*wr0 + a.y*wr1 + a.z*wr2 + a.w*wr3;
        }
    }
    float blc = bl[c], brc = br[c];
    #pragma unroll
    for (int r = 0; r < 16; r++) {
        xl[(n0 + r)*256 + c] = accl[r] + blc;
        xr[(n0 + r)*256 + c] = accr[r] + brc;
    }
}

// ---------------- per-edge attention logits ----------------
// one wave per edge; lane covers 4 contiguous channels; lanes 0-31 = head0, 32-63 = head1
__global__ void edge_alpha(const float* __restrict__ xl, const float* __restrict__ xr,
                           const float* __restrict__ We, const float* __restrict__ att,
                           const float* __restrict__ ew, const int* __restrict__ src,
                           const int* __restrict__ dst, float* __restrict__ alpha) {
    int e = blockIdx.x * 4 + (threadIdx.x >> 6);
    int lane = threadIdx.x & 63;
    if (e >= N_EDGES) return;
    int s = src[e], d = dst[e];
    float w = ew[e];
    float4 l4 = *(const float4*)(xl + s*256 + lane*4);
    float4 r4 = *(const float4*)(xr + d*256 + lane*4);
    float4 w4 = *(const float4*)(We + lane*4);
    float4 a4 = *(const float4*)(att + lane*4);
    float v, sum = 0.f;
    v = l4.x + r4.x + w*w4.x; v = v > 0.f ? v : NEG_SLOPE*v; sum += v*a4.x;
    v = l4.y + r4.y + w*w4.y; v = v > 0.f ? v : NEG_SLOPE*v; sum += v*a4.y;
    v = l4.z + r4.z + w*w4.z; v = v > 0.f ? v : NEG_SLOPE*v; sum += v*a4.z;
    v = l4.w + r4.w + w*w4.w; v = v > 0.f ? v : NEG_SLOPE*v; sum += v*a4.w;
    #pragma unroll
    for (int m = 1; m <= 16; m <<= 1) sum += __shfl_xor(sum, m, 64);
    if ((lane & 31) == 0) alpha[e*2 + (lane >> 5)] = sum;
}

// ---------------- per-node softmax + aggregation (concat=True, +bias) ----------------
__global__ void aggregate_concat(const float* __restrict__ xl, const float* __restrict__ alpha,
                                 const int* __restrict__ offsets, const int* __restrict__ perm,
                                 const int* __restrict__ src, const float* __restrict__ bias,
                                 float* __restrict__ out) {
    int n = blockIdx.x * 4 + (threadIdx.x >> 6);
    int lane = threadIdx.x & 63;
    if (n >= N_NODES) return;
    int hh = lane >> 5;
    int beg = offsets[n], end = offsets[n+1];
    float m = -INFINITY;
    for (int i = beg; i < end; i++) {
        int e = perm[i];
        m = fmaxf(m, alpha[e*2 + hh]);
    }
    float den = 0.f;
    float ax = 0.f, ay = 0.f, az = 0.f, aw = 0.f;
    for (int i = beg; i < end; i++) {
        int e = perm[i];
        float a = __expf(alpha[e*2 + hh] - m);
        den += a;
        int s = src[e];
        float4 v = *(const float4*)(xl + s*256 + lane*4);
        ax += a*v.x; ay += a*v.y; az += a*v.z; aw += a*v.w;
    }
    float inv = 1.f / (den + 1e-16f);
    float4 b4 = *(const float4*)(bias + lane*4);
    float4 o;
    o.x = ax*inv + b4.x; o.y = ay*inv + b4.y; o.z = az*inv + b4.z; o.w = aw*inv + b4.w;
    *(float4*)(out + n*256 + lane*4) = o;
}

// ---------------- per-node softmax + aggregation (concat=False: mean over heads, +bias) ----------------
__global__ void aggregate_mean(const float* __restrict__ xl, const float* __restrict__ alpha,
                               const int* __restrict__ offsets, const int* __restrict__ perm,
                               const int* __restrict__ src, const float* __restrict__ bias,
                               float* __restrict__ out) {
    int n = blockIdx.x * 4 + (threadIdx.x >> 6);
    int lane = threadIdx.x & 63;
    if (n >= N_NODES) return;
    int hh = lane >> 5;
    int beg = offsets[n], end = offsets[n+1];
    float m = -INFINITY;
    for (int i = beg; i < end; i++) {
        int e = perm[i];
        m = fmaxf(m, alpha[e*2 + hh]);
    }
    float den = 0.f;
    float ax = 0.f, ay = 0.f, az = 0.f, aw = 0.f;
    for (int i = beg; i < end; i++) {
        int e = perm[i];
        float a = __expf(alpha[e*2 + hh] - m);
        den += a;
        int s = src[e];
        float4 v = *(const float4*)(xl + s*256 + lane*4);
        ax += a*v.x; ay += a*v.y; az += a*v.z; aw += a*v.w;
    }
    float inv = 1.f / (den + 1e-16f);
    float ox = ax*inv, oy = ay*inv, oz = az*inv, ow = aw*inv;
    // head1 partner is lane+32 (same channel within head)
    float px = __shfl_xor(ox, 32, 64);
    float py = __shfl_xor(oy, 32, 64);
    float pz = __shfl_xor(oz, 32, 64);
    float pw = __shfl_xor(ow, 32, 64);
    if (lane < 32) {
        float4 b4 = *(const float4*)(bias + lane*4);
        float4 o;
        o.x = (ox + px)*0.5f + b4.x;
        o.y = (oy + py)*0.5f + b4.y;
        o.z = (oz + pz)*0.5f + b4.z;
        o.w = (ow + pw)*0.5f + b4.w;
        *(float4*)(out + n*128 + lane*4) = o;
    }
}

// ---------------- BN1 over [N,256] + ReLU ----------------
__global__ void bn1_reduce(const float* __restrict__ x, float* __restrict__ sum,
                           float* __restrict__ sumsq) {
    int c = threadIdx.x;
    int r0 = blockIdx.x * 196;
    int r1 = r0 + 196; if (r1 > N_NODES) r1 = N_NODES;
    float s = 0.f, q = 0.f;
    for (int r = r0; r < r1; r++) {
        float v = x[r*256 + c];
        s += v; q += v*v;
    }
    atomicAdd(&sum[c], s);
    atomicAdd(&sumsq[c], q);
}

__global__ void bn1_apply_relu(float* __restrict__ x, const float* __restrict__ sum,
                               const float* __restrict__ sumsq, const float* __restrict__ g,
                               const float* __restrict__ b) {
    int i = blockIdx.x * 256 + threadIdx.x;
    int c = i & 255;
    float mean = sum[c] * (1.f / N_NODES);
    float var  = sumsq[c] * (1.f / N_NODES) - mean*mean;
    float sc = g[c] * rsqrtf(var + BN_EPS);
    float v = (x[i] - mean) * sc + b[c];
    x[i] = v > 0.f ? v : 0.f;
}

extern "C" void kernel_launch(void* const* d_in, const int* in_sizes, int n_in,
                              void* d_out, int out_size, void* d_ws, size_t ws_size,
                              hipStream_t stream) {
    const float* h          = (const float*)d_in[0];
    const int*   edge_index = (const int*)d_in[1];
    const int*   src = edge_index;
    const int*   dst = edge_index + N_EDGES;
    const float* ew   = (const float*)d_in[2];
    const float* bn0g = (const float*)d_in[3];
    const float* bn0b = (const float*)d_in[4];
    const float* bn1g = (const float*)d_in[5];
    const float* bn1b = (const float*)d_in[6];
    const float* c1_Wl = (const float*)d_in[7];
    const float* c1_bl = (const float*)d_in[8];
    const float* c1_Wr = (const float*)d_in[9];
    const float* c1_br = (const float*)d_in[10];
    const float* c1_We = (const float*)d_in[11];
    const float* c1_att = (const float*)d_in[12];
    const float* c1_bias = (const float*)d_in[13];
    const float* mu_Wl = (const float*)d_in[14];
    const float* mu_bl = (const float*)d_in[15];
    const float* mu_Wr = (const float*)d_in[16];
    const float* mu_br = (const float*)d_in[17];
    const float* mu_We = (const float*)d_in[18];
    const float* mu_att = (const float*)d_in[19];
    const float* mu_bias = (const float*)d_in[20];
    const float* ls_Wl = (const float*)d_in[21];
    const float* ls_bl = (const float*)d_in[22];
    const float* ls_Wr = (const float*)d_in[23];
    const float* ls_br = (const float*)d_in[24];
    const float* ls_We = (const float*)d_in[25];
    const float* ls_att = (const float*)d_in[26];
    const float* ls_bias = (const float*)d_in[27];

    float* out_mu = (float*)d_out;
    float* out_ls = (float*)d_out + (size_t)N_NODES * 128;

    // workspace carve-up (256B aligned blocks); total ~159 MB
    char* ws = (char*)d_ws;
    size_t off = 0;
    auto alloc = [&](size_t bytes) -> void* {
        void* p = ws + off;
        off += (bytes + 255) / 256 * 256;
        return p;
    };
    float* x0      = (float*)alloc((size_t)N_NODES * 5 * 4);
    float* xl      = (float*)alloc((size_t)N_NODES * 256 * 4);
    float* xr      = (float*)alloc((size_t)N_NODES * 256 * 4);
    float* xB      = (float*)alloc((size_t)N_NODES * 256 * 4);
    float* alpha   = (float*)alloc((size_t)N_EDGES * 2 * 4);
    float* bn0ss   = (float*)alloc(10 * 4);
    float* bn1sum  = (float*)alloc(256 * 4);
    float* bn1sq   = (float*)alloc(256 * 4);
    int*   count   = (int*)alloc((size_t)N_NODES * 4);
    int*   offsets = (int*)alloc((size_t)(N_NODES + 1) * 4);
    int*   cursor  = (int*)alloc((size_t)N_NODES * 4);
    int*   perm    = (int*)alloc((size_t)N_EDGES * 4);

    hipMemsetAsync(count, 0, (size_t)N_NODES * 4, stream);
    hipMemsetAsync(bn1sum, 0, 256 * 4, stream);
    hipMemsetAsync(bn1sq, 0, 256 * 4, stream);

    // BN0
    bn0_stats<<<1, 256, 0, stream>>>(h, bn0g, bn0b, bn0ss);
    bn0_apply<<<(N_NODES * 5 + 255) / 256, 256, 0, stream>>>(h, bn0ss, x0);

    // CSR by dst (shared by all 3 convs)
    edge_count<<<(N_EDGES + 255) / 256, 256, 0, stream>>>(dst, count);
    scan_offsets<<<1, 1024, 0, stream>>>(count, offsets, cursor);
    edge_scatter<<<(N_EDGES + 255) / 256, 256, 0, stream>>>(dst, cursor, perm);

    // conv1 (concat)
    gemm_k5<<<N_NODES, 256, 0, stream>>>(x0, c1_Wl, c1_bl, c1_Wr, c1_br, xl, xr);
    edge_alpha<<<N_EDGES / 4, 256, 0, stream>>>(xl, xr, c1_We, c1_att, ew, src, dst, alpha);
    aggregate_concat<<<N_NODES / 4 + 1, 256, 0, stream>>>(xl, alpha, offsets, perm, src, c1_bias, xB);

    // BN1 + ReLU
    bn1_reduce<<<256, 256, 0, stream>>>(xB, bn1sum, bn1sq);
    bn1_apply_relu<<<N_NODES, 256, 0, stream>>>(xB, bn1sum, bn1sq, bn1g, bn1b);

    // mu conv (head-mean)
    gemm_k256<<<N_NODES / 16, 256, 0, stream>>>(xB, mu_Wl, mu_bl, mu_Wr, mu_br, xl, xr);
    edge_alpha<<<N_EDGES / 4, 256, 0, stream>>>(xl, xr, mu_We, mu_att, ew, src, dst, alpha);
    aggregate_mean<<<N_NODES / 4 + 1, 256, 0, stream>>>(xl, alpha, offsets, perm, src, mu_bias, out_mu);

    // log_std conv (head-mean)
    gemm_k256<<<N_NODES / 16, 256, 0, stream>>>(xB, ls_Wl, ls_bl, ls_Wr, ls_br, xl, xr);
    edge_alpha<<<N_EDGES / 4, 256, 0, stream>>>(xl, xr, ls_We, ls_att, ew, src, dst, alpha);
    aggregate_mean<<<N_NODES / 4 + 1, 256, 0, stream>>>(xl, alpha, offsets, perm, src, ls_bias, out_ls);
}

// Round 2
// 1072.091 us; speedup vs baseline: 1.2884x; 1.2884x over previous
//
#include <hip/hip_runtime.h>
#include <math.h>

#define N_NODES 50000
#define N_EDGES 300000
#define BN_EPS 1e-5f
#define NEG_SLOPE 0.2f

// 50000 rows pad to 3128 row-blocks of 16 (50048)
#define RB_COUNT 3128

typedef short bf8v __attribute__((ext_vector_type(8)));
typedef float f4v __attribute__((ext_vector_type(4)));

__device__ inline unsigned short f2bf(float f) {
    union { float f; unsigned u; } c; c.f = f;
    unsigned r = c.u + 0x7fffu + ((c.u >> 16) & 1u);
    return (unsigned short)(r >> 16);
}

// ---------------- BN0 (5 columns) ----------------
__global__ void bn0_stats(const float* __restrict__ h, const float* __restrict__ g,
                          const float* __restrict__ b, float* __restrict__ ss /*[10]: scale,shift*/) {
    __shared__ float s_sum[5], s_sq[5];
    int tid = threadIdx.x;
    if (tid < 5) { s_sum[tid] = 0.f; s_sq[tid] = 0.f; }
    __syncthreads();
    float ls[5] = {0,0,0,0,0}, lq[5] = {0,0,0,0,0};
    for (int r = tid; r < N_NODES; r += blockDim.x) {
        #pragma unroll
        for (int k = 0; k < 5; k++) {
            float v = h[r*5 + k];
            ls[k] += v; lq[k] += v*v;
        }
    }
    #pragma unroll
    for (int k = 0; k < 5; k++) { atomicAdd(&s_sum[k], ls[k]); atomicAdd(&s_sq[k], lq[k]); }
    __syncthreads();
    if (tid < 5) {
        float mean = s_sum[tid] * (1.f / N_NODES);
        float var  = s_sq[tid] * (1.f / N_NODES) - mean*mean;
        float sc = g[tid] * rsqrtf(var + BN_EPS);
        ss[tid]     = sc;
        ss[5 + tid] = b[tid] - mean * sc;
    }
}

__global__ void bn0_apply(const float* __restrict__ h, const float* __restrict__ ss,
                          float* __restrict__ x0) {
    int i = blockIdx.x * blockDim.x + threadIdx.x;
    if (i < N_NODES * 5) {
        int k = i % 5;
        x0[i] = h[i] * ss[k] + ss[5 + k];
    }
}

// ---------------- CSR build by dst ----------------
__global__ void edge_count(const int* __restrict__ dst, int* __restrict__ count) {
    int e = blockIdx.x * blockDim.x + threadIdx.x;
    if (e < N_EDGES) atomicAdd(&count[dst[e]], 1);
}

__global__ void scan_offsets(const int* __restrict__ count, int* __restrict__ offsets,
                             int* __restrict__ cursor) {
    __shared__ int lds[1024];
    __shared__ int carry;
    int tid = threadIdx.x;
    if (tid == 0) carry = 0;
    __syncthreads();
    for (int base = 0; base < N_NODES; base += 1024) {
        int v = (base + tid < N_NODES) ? count[base + tid] : 0;
        lds[tid] = v;
        __syncthreads();
        for (int off = 1; off < 1024; off <<= 1) {
            int t = (tid >= off) ? lds[tid - off] : 0;
            __syncthreads();
            lds[tid] += t;
            __syncthreads();
        }
        int excl = carry + lds[tid] - v;
        if (base + tid < N_NODES) { offsets[base + tid] = excl; cursor[base + tid] = excl; }
        __syncthreads();
        if (tid == 0) carry += lds[1023];
        __syncthreads();
    }
    if (tid == 0) offsets[N_NODES] = carry;
}

__global__ void edge_scatter(const int* __restrict__ dst, int* __restrict__ cursor,
                             int* __restrict__ perm) {
    int e = blockIdx.x * blockDim.x + threadIdx.x;
    if (e < N_EDGES) {
        int pos = atomicAdd(&cursor[dst[e]], 1);
        perm[pos] = e;
    }
}

// ---------------- conv1 linear (K=5) ----------------
__global__ void gemm_k5(const float* __restrict__ x0,
                        const float* __restrict__ Wl, const float* __restrict__ bl,
                        const float* __restrict__ Wr, const float* __restrict__ br,
                        float* __restrict__ xl, float* __restrict__ xr) {
    int n = blockIdx.x;
    int c = threadIdx.x;
    float a0 = x0[n*5+0], a1 = x0[n*5+1], a2 = x0[n*5+2], a3 = x0[n*5+3], a4 = x0[n*5+4];
    float l = bl[c] + a0*Wl[c] + a1*Wl[256+c] + a2*Wl[512+c] + a3*Wl[768+c] + a4*Wl[1024+c];
    float r = br[c] + a0*Wr[c] + a1*Wr[256+c] + a2*Wr[512+c] + a3*Wr[768+c] + a4*Wr[1024+c];
    xl[n*256 + c] = l;
    xr[n*256 + c] = r;
}

// ---------------- pack X (fp32 [50000x256] -> bf16 MFMA A-fragment order) ----------------
// layout: [rb][kc][lane][j], elem = X[rb*16 + (lane&15)][kc*32 + (lane>>4)*8 + j]
__global__ void pack_x(const float* __restrict__ x, unsigned short* __restrict__ ap) {
    int t = blockIdx.x * 256 + threadIdx.x;   // RB_COUNT*8*64 = 1601536 threads exact
    int lane = t & 63;
    int kc = (t >> 6) & 7;
    int rb = t >> 9;
    int row = rb * 16 + (lane & 15);
    int k0 = kc * 32 + (lane >> 4) * 8;
    union { unsigned short h[8]; uint4 u; } tmp;
    if (row < N_NODES) {
        const float* s = x + (size_t)row * 256 + k0;
        #pragma unroll
        for (int j = 0; j < 8; j++) tmp.h[j] = f2bf(s[j]);
    } else {
        #pragma unroll
        for (int j = 0; j < 8; j++) tmp.h[j] = 0;
    }
    *reinterpret_cast<uint4*>(ap + (size_t)t * 8) = tmp.u;
}

// ---------------- pack W for both convs (fp32 -> bf16 MFMA B-fragment order) ----------------
// layout per conv: [kc][nt][lane][j], elem = W[k = kc*32+(lane>>4)*8+j][col = nt*16+(lane&15)]
// cols 0..255 from Wl, 256..511 from Wr. conv stride = 8*32*64*8 = 131072 elems.
__global__ void pack_w(const float* __restrict__ Wl0, const float* __restrict__ Wr0,
                       const float* __restrict__ Wl1, const float* __restrict__ Wr1,
                       unsigned short* __restrict__ bp) {
    int t = blockIdx.x * 256 + threadIdx.x;   // 2*8*32*64 = 32768 threads exact
    int lane = t & 63;
    int nt = (t >> 6) & 31;
    int kc = (t >> 11) & 7;
    int conv = t >> 14;
    int col = nt * 16 + (lane & 15);
    int k0 = kc * 32 + (lane >> 4) * 8;
    const float* W = conv ? (col < 256 ? Wl1 : Wr1) : (col < 256 ? Wl0 : Wr0);
    int c = col & 255;
    union { unsigned short h[8]; uint4 u; } tmp;
    #pragma unroll
    for (int j = 0; j < 8; j++) tmp.h[j] = f2bf(W[(size_t)(k0 + j) * 256 + c]);
    *reinterpret_cast<uint4*>(bp + (size_t)t * 8) = tmp.u;
}

// ---------------- big linear via MFMA: C[50000x512] = X[50000x256] @ [Wl|Wr] ----------------
// block = 512 threads = 8 waves: wave>>1 selects row-slice (rb), wave&1 selects col half
// (h=0 -> xl cols 0..255, h=1 -> xr cols 0..255). Grid 782 blocks x 4 rb = 3128 rb.
__global__ __launch_bounds__(512) void gemm_mfma(const unsigned short* __restrict__ ap,
        const unsigned short* __restrict__ bp,
        const float* __restrict__ bl, const float* __restrict__ br,
        float* __restrict__ xl, float* __restrict__ xr) {
    int lane = threadIdx.x & 63;
    int wave = threadIdx.x >> 6;
    int h = wave & 1;
    int rb = blockIdx.x * 4 + (wave >> 1);
    f4v acc[16];
    #pragma unroll
    for (int t = 0; t < 16; t++) acc[t] = (f4v){0.f, 0.f, 0.f, 0.f};
    const unsigned short* aptr = ap + (size_t)rb * 4096 + lane * 8;
    const unsigned short* bptr = bp + (size_t)h * 8192 + lane * 8;
    for (int kc = 0; kc < 8; kc++) {
        bf8v a = *reinterpret_cast<const bf8v*>(aptr + kc * 512);
        const unsigned short* bb = bptr + (size_t)kc * 16384;
        #pragma unroll
        for (int t = 0; t < 16; t++) {
            bf8v b = *reinterpret_cast<const bf8v*>(bb + t * 512);
            acc[t] = __builtin_amdgcn_mfma_f32_16x16x32_bf16(a, b, acc[t], 0, 0, 0);
        }
    }
    int c15 = lane & 15;
    int row0 = rb * 16 + (lane >> 4) * 4;
    float* outp = h ? xr : xl;
    const float* bias = h ? br : bl;
    #pragma unroll
    for (int t = 0; t < 16; t++) {
        int col = t * 16 + c15;
        float bv = bias[col];
        #pragma unroll
        for (int r = 0; r < 4; r++) {
            int row = row0 + r;
            if (row < N_NODES) outp[(size_t)row * 256 + col] = acc[t][r] + bv;
        }
    }
}

// ---------------- per-edge attention logits ----------------
// one wave per edge; lane covers 4 contiguous channels; lanes 0-31 = head0, 32-63 = head1
__global__ void edge_alpha(const float* __restrict__ xl, const float* __restrict__ xr,
                           const float* __restrict__ We, const float* __restrict__ att,
                           const float* __restrict__ ew, const int* __restrict__ src,
                           const int* __restrict__ dst, float* __restrict__ alpha) {
    int e = blockIdx.x * 4 + (threadIdx.x >> 6);
    int lane = threadIdx.x & 63;
    if (e >= N_EDGES) return;
    int s = src[e], d = dst[e];
    float w = ew[e];
    float4 l4 = *(const float4*)(xl + s*256 + lane*4);
    float4 r4 = *(const float4*)(xr + d*256 + lane*4);
    float4 w4 = *(const float4*)(We + lane*4);
    float4 a4 = *(const float4*)(att + lane*4);
    float v, sum = 0.f;
    v = l4.x + r4.x + w*w4.x; v = v > 0.f ? v : NEG_SLOPE*v; sum += v*a4.x;
    v = l4.y + r4.y + w*w4.y; v = v > 0.f ? v : NEG_SLOPE*v; sum += v*a4.y;
    v = l4.z + r4.z + w*w4.z; v = v > 0.f ? v : NEG_SLOPE*v; sum += v*a4.z;
    v = l4.w + r4.w + w*w4.w; v = v > 0.f ? v : NEG_SLOPE*v; sum += v*a4.w;
    #pragma unroll
    for (int m = 1; m <= 16; m <<= 1) sum += __shfl_xor(sum, m, 64);
    if ((lane & 31) == 0) alpha[e*2 + (lane >> 5)] = sum;
}

// ---------------- per-node softmax + aggregation (concat=True, +bias) ----------------
__global__ void aggregate_concat(const float* __restrict__ xl, const float* __restrict__ alpha,
                                 const int* __restrict__ offsets, const int* __restrict__ perm,
                                 const int* __restrict__ src, const float* __restrict__ bias,
                                 float* __restrict__ out) {
    int n = blockIdx.x * 4 + (threadIdx.x >> 6);
    int lane = threadIdx.x & 63;
    if (n >= N_NODES) return;
    int hh = lane >> 5;
    int beg = offsets[n], end = offsets[n+1];
    float m = -INFINITY;
    for (int i = beg; i < end; i++) {
        int e = perm[i];
        m = fmaxf(m, alpha[e*2 + hh]);
    }
    float den = 0.f;
    float ax = 0.f, ay = 0.f, az = 0.f, aw = 0.f;
    for (int i = beg; i < end; i++) {
        int e = perm[i];
        float a = __expf(alpha[e*2 + hh] - m);
        den += a;
        int s = src[e];
        float4 v = *(const float4*)(xl + s*256 + lane*4);
        ax += a*v.x; ay += a*v.y; az += a*v.z; aw += a*v.w;
    }
    float inv = 1.f / (den + 1e-16f);
    float4 b4 = *(const float4*)(bias + lane*4);
    float4 o;
    o.x = ax*inv + b4.x; o.y = ay*inv + b4.y; o.z = az*inv + b4.z; o.w = aw*inv + b4.w;
    *(float4*)(out + n*256 + lane*4) = o;
}

// ---------------- per-node softmax + aggregation (concat=False: mean over heads, +bias) ----------------
__global__ void aggregate_mean(const float* __restrict__ xl, const float* __restrict__ alpha,
                               const int* __restrict__ offsets, const int* __restrict__ perm,
                               const int* __restrict__ src, const float* __restrict__ bias,
                               float* __restrict__ out) {
    int n = blockIdx.x * 4 + (threadIdx.x >> 6);
    int lane = threadIdx.x & 63;
    if (n >= N_NODES) return;
    int hh = lane >> 5;
    int beg = offsets[n], end = offsets[n+1];
    float m = -INFINITY;
    for (int i = beg; i < end; i++) {
        int e = perm[i];
        m = fmaxf(m, alpha[e*2 + hh]);
    }
    float den = 0.f;
    float ax = 0.f, ay = 0.f, az = 0.f, aw = 0.f;
    for (int i = beg; i < end; i++) {
        int e = perm[i];
        float a = __expf(alpha[e*2 + hh] - m);
        den += a;
        int s = src[e];
        float4 v = *(const float4*)(xl + s*256 + lane*4);
        ax += a*v.x; ay += a*v.y; az += a*v.z; aw += a*v.w;
    }
    float inv = 1.f / (den + 1e-16f);
    float ox = ax*inv, oy = ay*inv, oz = az*inv, ow = aw*inv;
    // head1 partner is lane+32 (same channel within head)
    float px = __shfl_xor(ox, 32, 64);
    float py = __shfl_xor(oy, 32, 64);
    float pz = __shfl_xor(oz, 32, 64);
    float pw = __shfl_xor(ow, 32, 64);
    if (lane < 32) {
        float4 b4 = *(const float4*)(bias + lane*4);
        float4 o;
        o.x = (ox + px)*0.5f + b4.x;
        o.y = (oy + py)*0.5f + b4.y;
        o.z = (oz + pz)*0.5f + b4.z;
        o.w = (ow + pw)*0.5f + b4.w;
        *(float4*)(out + n*128 + lane*4) = o;
    }
}

// ---------------- BN1 over [N,256] + ReLU ----------------
__global__ void bn1_reduce(const float* __restrict__ x, float* __restrict__ sum,
                           float* __restrict__ sumsq) {
    int c = threadIdx.x;
    int r0 = blockIdx.x * 196;
    int r1 = r0 + 196; if (r1 > N_NODES) r1 = N_NODES;
    float s = 0.f, q = 0.f;
    for (int r = r0; r < r1; r++) {
        float v = x[r*256 + c];
        s += v; q += v*v;
    }
    atomicAdd(&sum[c], s);
    atomicAdd(&sumsq[c], q);
}

__global__ void bn1_apply_relu(float* __restrict__ x, const float* __restrict__ sum,
                               const float* __restrict__ sumsq, const float* __restrict__ g,
                               const float* __restrict__ b) {
    int i = blockIdx.x * 256 + threadIdx.x;
    int c = i & 255;
    float mean = sum[c] * (1.f / N_NODES);
    float var  = sumsq[c] * (1.f / N_NODES) - mean*mean;
    float sc = g[c] * rsqrtf(var + BN_EPS);
    float v = (x[i] - mean) * sc + b[c];
    x[i] = v > 0.f ? v : 0.f;
}

extern "C" void kernel_launch(void* const* d_in, const int* in_sizes, int n_in,
                              void* d_out, int out_size, void* d_ws, size_t ws_size,
                              hipStream_t stream) {
    const float* h          = (const float*)d_in[0];
    const int*   edge_index = (const int*)d_in[1];
    const int*   src = edge_index;
    const int*   dst = edge_index + N_EDGES;
    const float* ew   = (const float*)d_in[2];
    const float* bn0g = (const float*)d_in[3];
    const float* bn0b = (const float*)d_in[4];
    const float* bn1g = (const float*)d_in[5];
    const float* bn1b = (const float*)d_in[6];
    const float* c1_Wl = (const float*)d_in[7];
    const float* c1_bl = (const float*)d_in[8];
    const float* c1_Wr = (const float*)d_in[9];
    const float* c1_br = (const float*)d_in[10];
    const float* c1_We = (const float*)d_in[11];
    const float* c1_att = (const float*)d_in[12];
    const float* c1_bias = (const float*)d_in[13];
    const float* mu_Wl = (const float*)d_in[14];
    const float* mu_bl = (const float*)d_in[15];
    const float* mu_Wr = (const float*)d_in[16];
    const float* mu_br = (const float*)d_in[17];
    const float* mu_We = (const float*)d_in[18];
    const float* mu_att = (const float*)d_in[19];
    const float* mu_bias = (const float*)d_in[20];
    const float* ls_Wl = (const float*)d_in[21];
    const float* ls_bl = (const float*)d_in[22];
    const float* ls_Wr = (const float*)d_in[23];
    const float* ls_br = (const float*)d_in[24];
    const float* ls_We = (const float*)d_in[25];
    const float* ls_att = (const float*)d_in[26];
    const float* ls_bias = (const float*)d_in[27];

    float* out_mu = (float*)d_out;
    float* out_ls = (float*)d_out + (size_t)N_NODES * 128;

    // workspace carve-up (256B aligned blocks); total ~186 MB
    char* ws = (char*)d_ws;
    size_t off = 0;
    auto alloc = [&](size_t bytes) -> void* {
        void* p = ws + off;
        off += (bytes + 255) / 256 * 256;
        return p;
    };
    float* x0      = (float*)alloc((size_t)N_NODES * 5 * 4);
    float* xl      = (float*)alloc((size_t)N_NODES * 256 * 4);
    float* xr      = (float*)alloc((size_t)N_NODES * 256 * 4);
    float* xB      = (float*)alloc((size_t)N_NODES * 256 * 4);
    float* alpha   = (float*)alloc((size_t)N_EDGES * 2 * 4);
    float* bn0ss   = (float*)alloc(10 * 4);
    float* bn1sum  = (float*)alloc(256 * 4);
    float* bn1sq   = (float*)alloc(256 * 4);
    int*   count   = (int*)alloc((size_t)N_NODES * 4);
    int*   offsets = (int*)alloc((size_t)(N_NODES + 1) * 4);
    int*   cursor  = (int*)alloc((size_t)N_NODES * 4);
    int*   perm    = (int*)alloc((size_t)N_EDGES * 4);
    unsigned short* Apack = (unsigned short*)alloc((size_t)RB_COUNT * 4096 * 2);  // 25.6 MB
    unsigned short* Bpack = (unsigned short*)alloc((size_t)2 * 131072 * 2);       // 512 KB

    hipMemsetAsync(count, 0, (size_t)N_NODES * 4, stream);
    hipMemsetAsync(bn1sum, 0, 256 * 4, stream);
    hipMemsetAsync(bn1sq, 0, 256 * 4, stream);

    // BN0
    bn0_stats<<<1, 256, 0, stream>>>(h, bn0g, bn0b, bn0ss);
    bn0_apply<<<(N_NODES * 5 + 255) / 256, 256, 0, stream>>>(h, bn0ss, x0);

    // CSR by dst (shared by all 3 convs)
    edge_count<<<(N_EDGES + 255) / 256, 256, 0, stream>>>(dst, count);
    scan_offsets<<<1, 1024, 0, stream>>>(count, offsets, cursor);
    edge_scatter<<<(N_EDGES + 255) / 256, 256, 0, stream>>>(dst, cursor, perm);

    // pack mu/ls weights to bf16 fragment order (independent of graph data)
    pack_w<<<128, 256, 0, stream>>>(mu_Wl, mu_Wr, ls_Wl, ls_Wr, Bpack);

    // conv1 (concat)
    gemm_k5<<<N_NODES, 256, 0, stream>>>(x0, c1_Wl, c1_bl, c1_Wr, c1_br, xl, xr);
    edge_alpha<<<N_EDGES / 4, 256, 0, stream>>>(xl, xr, c1_We, c1_att, ew, src, dst, alpha);
    aggregate_concat<<<N_NODES / 4 + 1, 256, 0, stream>>>(xl, alpha, offsets, perm, src, c1_bias, xB);

    // BN1 + ReLU
    bn1_reduce<<<256, 256, 0, stream>>>(xB, bn1sum, bn1sq);
    bn1_apply_relu<<<N_NODES, 256, 0, stream>>>(xB, bn1sum, bn1sq, bn1g, bn1b);

    // pack activations once (mu and ls share the same input)
    pack_x<<<6256, 256, 0, stream>>>(xB, Apack);

    // mu conv (head-mean)
    gemm_mfma<<<782, 512, 0, stream>>>(Apack, Bpack, mu_bl, mu_br, xl, xr);
    edge_alpha<<<N_EDGES / 4, 256, 0, stream>>>(xl, xr, mu_We, mu_att, ew, src, dst, alpha);
    aggregate_mean<<<N_NODES / 4 + 1, 256, 0, stream>>>(xl, alpha, offsets, perm, src, mu_bias, out_mu);

    // log_std conv (head-mean)
    gemm_mfma<<<782, 512, 0, stream>>>(Apack, Bpack + 131072, ls_bl, ls_br, xl, xr);
    edge_alpha<<<N_EDGES / 4, 256, 0, stream>>>(xl, xr, ls_We, ls_att, ew, src, dst, alpha);
    aggregate_mean<<<N_NODES / 4 + 1, 256, 0, stream>>>(xl, alpha, offsets, perm, src, ls_bias, out_ls);
}

// Round 3
// 889.972 us; speedup vs baseline: 1.5521x; 1.2046x over previous
//
#include <hip/hip_runtime.h>
#include <math.h>

#define N_NODES 50000
#define N_EDGES 300000
#define BN_EPS 1e-5f
#define NEG_SLOPE 0.2f

// 50000 rows pad to 3128 row-blocks of 16 (50048)
#define RB_COUNT 3128
#define SCAN_TILES 49   // 49*1024 = 50176 >= N_NODES

typedef short bf8v __attribute__((ext_vector_type(8)));
typedef float f4v __attribute__((ext_vector_type(4)));

__device__ inline unsigned short f2bf(float f) {
    union { float f; unsigned u; } c; c.f = f;
    unsigned r = c.u + 0x7fffu + ((c.u >> 16) & 1u);
    return (unsigned short)(r >> 16);
}

// ---------------- BN0 (5 columns), grid-parallel ----------------
__global__ void bn0_reduce(const float* __restrict__ h, float* __restrict__ acc /*[10]*/) {
    __shared__ float lds[4][10];
    int tid = threadIdx.x;
    int lane = tid & 63, wave = tid >> 6;
    float ls[5] = {0,0,0,0,0}, lq[5] = {0,0,0,0,0};
    for (int r = blockIdx.x * 256 + tid; r < N_NODES; r += 128 * 256) {
        #pragma unroll
        for (int k = 0; k < 5; k++) {
            float v = h[r*5 + k];
            ls[k] += v; lq[k] += v*v;
        }
    }
    #pragma unroll
    for (int k = 0; k < 5; k++) {
        #pragma unroll
        for (int m = 1; m <= 32; m <<= 1) {
            ls[k] += __shfl_xor(ls[k], m, 64);
            lq[k] += __shfl_xor(lq[k], m, 64);
        }
    }
    if (lane == 0) {
        #pragma unroll
        for (int k = 0; k < 5; k++) { lds[wave][k] = ls[k]; lds[wave][5+k] = lq[k]; }
    }
    __syncthreads();
    if (tid < 10) {
        float s = lds[0][tid] + lds[1][tid] + lds[2][tid] + lds[3][tid];
        atomicAdd(&acc[tid], s);
    }
}

__global__ void bn0_finalize(const float* __restrict__ acc, const float* __restrict__ g,
                             const float* __restrict__ b, float* __restrict__ ss) {
    int tid = threadIdx.x;
    if (tid < 5) {
        float mean = acc[tid] * (1.f / N_NODES);
        float var  = acc[5 + tid] * (1.f / N_NODES) - mean*mean;
        float sc = g[tid] * rsqrtf(var + BN_EPS);
        ss[tid]     = sc;
        ss[5 + tid] = b[tid] - mean * sc;
    }
}

__global__ void bn0_apply(const float* __restrict__ h, const float* __restrict__ ss,
                          float* __restrict__ x0) {
    int i = blockIdx.x * blockDim.x + threadIdx.x;
    if (i < N_NODES * 5) {
        int k = i % 5;
        x0[i] = h[i] * ss[k] + ss[5 + k];
    }
}

// ---------------- CSR build by dst ----------------
__global__ void edge_count(const int* __restrict__ dst, int* __restrict__ count) {
    int e = blockIdx.x * blockDim.x + threadIdx.x;
    if (e < N_EDGES) atomicAdd(&count[dst[e]], 1);
}

// two-level scan: per-tile local exclusive scan + tile totals
__global__ void local_scan(const int* __restrict__ count, int* __restrict__ offsets,
                           int* __restrict__ tileSum) {
    __shared__ int lds[1024];
    int tid = threadIdx.x;
    int i = blockIdx.x * 1024 + tid;
    int v = (i < N_NODES) ? count[i] : 0;
    lds[tid] = v;
    __syncthreads();
    #pragma unroll
    for (int off = 1; off < 1024; off <<= 1) {
        int t = (tid >= off) ? lds[tid - off] : 0;
        __syncthreads();
        lds[tid] += t;
        __syncthreads();
    }
    if (i < N_NODES) offsets[i] = lds[tid] - v;   // local exclusive
    if (tid == 1023) tileSum[blockIdx.x] = lds[1023];
}

__global__ void tile_scan(const int* __restrict__ tileSum, int* __restrict__ tilePrefix,
                          int* __restrict__ offsets) {
    int lane = threadIdx.x;
    int v = (lane < SCAN_TILES) ? tileSum[lane] : 0;
    int inc = v;
    #pragma unroll
    for (int off = 1; off < 64; off <<= 1) {
        int t = __shfl_up(inc, off, 64);
        if (lane >= off) inc += t;
    }
    int excl = inc - v;
    if (lane < SCAN_TILES) tilePrefix[lane] = excl;
    if (lane == SCAN_TILES - 1) offsets[N_NODES] = inc;
}

__global__ void add_prefix(int* __restrict__ offsets, const int* __restrict__ tilePrefix,
                           int* __restrict__ cursor) {
    int i = blockIdx.x * 1024 + threadIdx.x;
    if (i < N_NODES) {
        int o = offsets[i] + tilePrefix[blockIdx.x];
        offsets[i] = o;
        cursor[i] = o;
    }
}

__global__ void edge_scatter(const int* __restrict__ dst, int* __restrict__ cursor,
                             int* __restrict__ perm) {
    int e = blockIdx.x * blockDim.x + threadIdx.x;
    if (e < N_EDGES) {
        int pos = atomicAdd(&cursor[dst[e]], 1);
        perm[pos] = e;
    }
}

// ---------------- conv1 linear (K=5) ----------------
__global__ void gemm_k5(const float* __restrict__ x0,
                        const float* __restrict__ Wl, const float* __restrict__ bl,
                        const float* __restrict__ Wr, const float* __restrict__ br,
                        float* __restrict__ xl, float* __restrict__ xr) {
    int n = blockIdx.x;
    int c = threadIdx.x;
    float a0 = x0[n*5+0], a1 = x0[n*5+1], a2 = x0[n*5+2], a3 = x0[n*5+3], a4 = x0[n*5+4];
    float l = bl[c] + a0*Wl[c] + a1*Wl[256+c] + a2*Wl[512+c] + a3*Wl[768+c] + a4*Wl[1024+c];
    float r = br[c] + a0*Wr[c] + a1*Wr[256+c] + a2*Wr[512+c] + a3*Wr[768+c] + a4*Wr[1024+c];
    xl[n*256 + c] = l;
    xr[n*256 + c] = r;
}

// ---------------- pack X (fp32 [50000x256] -> bf16 MFMA A-fragment order) ----------------
// layout: [rb][kc][lane][j], elem = X[rb*16 + (lane&15)][kc*32 + (lane>>4)*8 + j]
__global__ void pack_x(const float* __restrict__ x, unsigned short* __restrict__ ap) {
    int t = blockIdx.x * 256 + threadIdx.x;   // RB_COUNT*8*64 = 1601536 threads exact
    int lane = t & 63;
    int kc = (t >> 6) & 7;
    int rb = t >> 9;
    int row = rb * 16 + (lane & 15);
    int k0 = kc * 32 + (lane >> 4) * 8;
    union { unsigned short h[8]; uint4 u; } tmp;
    if (row < N_NODES) {
        const float* s = x + (size_t)row * 256 + k0;
        #pragma unroll
        for (int j = 0; j < 8; j++) tmp.h[j] = f2bf(s[j]);
    } else {
        #pragma unroll
        for (int j = 0; j < 8; j++) tmp.h[j] = 0;
    }
    *reinterpret_cast<uint4*>(ap + (size_t)t * 8) = tmp.u;
}

// ---------------- pack W for both convs (fp32 -> bf16 MFMA B-fragment order) ----------------
// layout per conv: [kc][nt][lane][j], elem = W[k = kc*32+(lane>>4)*8+j][col = nt*16+(lane&15)]
// cols 0..255 from Wl, 256..511 from Wr. conv stride = 8*32*64*8 = 131072 elems.
__global__ void pack_w(const float* __restrict__ Wl0, const float* __restrict__ Wr0,
                       const float* __restrict__ Wl1, const float* __restrict__ Wr1,
                       unsigned short* __restrict__ bp) {
    int t = blockIdx.x * 256 + threadIdx.x;   // 2*8*32*64 = 32768 threads exact
    int lane = t & 63;
    int nt = (t >> 6) & 31;
    int kc = (t >> 11) & 7;
    int conv = t >> 14;
    int col = nt * 16 + (lane & 15);
    int k0 = kc * 32 + (lane >> 4) * 8;
    const float* W = conv ? (col < 256 ? Wl1 : Wr1) : (col < 256 ? Wl0 : Wr0);
    int c = col & 255;
    union { unsigned short h[8]; uint4 u; } tmp;
    #pragma unroll
    for (int j = 0; j < 8; j++) tmp.h[j] = f2bf(W[(size_t)(k0 + j) * 256 + c]);
    *reinterpret_cast<uint4*>(bp + (size_t)t * 8) = tmp.u;
}

// ---------------- big linear via MFMA: C[50000x512] = X[50000x256] @ [Wl|Wr] ----------------
// block = 512 threads = 8 waves: wave>>1 selects row-slice (rb), wave&1 selects col half
// (h=0 -> xl cols 0..255, h=1 -> xr cols 0..255). Grid 782 blocks x 4 rb = 3128 rb.
__global__ __launch_bounds__(512) void gemm_mfma(const unsigned short* __restrict__ ap,
        const unsigned short* __restrict__ bp,
        const float* __restrict__ bl, const float* __restrict__ br,
        float* __restrict__ xl, float* __restrict__ xr) {
    int lane = threadIdx.x & 63;
    int wave = threadIdx.x >> 6;
    int h = wave & 1;
    int rb = blockIdx.x * 4 + (wave >> 1);
    f4v acc[16];
    #pragma unroll
    for (int t = 0; t < 16; t++) acc[t] = (f4v){0.f, 0.f, 0.f, 0.f};
    const unsigned short* aptr = ap + (size_t)rb * 4096 + lane * 8;
    const unsigned short* bptr = bp + (size_t)h * 8192 + lane * 8;
    for (int kc = 0; kc < 8; kc++) {
        bf8v a = *reinterpret_cast<const bf8v*>(aptr + kc * 512);
        const unsigned short* bb = bptr + (size_t)kc * 16384;
        #pragma unroll
        for (int t = 0; t < 16; t++) {
            bf8v b = *reinterpret_cast<const bf8v*>(bb + t * 512);
            acc[t] = __builtin_amdgcn_mfma_f32_16x16x32_bf16(a, b, acc[t], 0, 0, 0);
        }
    }
    int c15 = lane & 15;
    int row0 = rb * 16 + (lane >> 4) * 4;
    float* outp = h ? xr : xl;
    const float* bias = h ? br : bl;
    #pragma unroll
    for (int t = 0; t < 16; t++) {
        int col = t * 16 + c15;
        float bv = bias[col];
        #pragma unroll
        for (int r = 0; r < 4; r++) {
            int row = row0 + r;
            if (row < N_NODES) outp[(size_t)row * 256 + col] = acc[t][r] + bv;
        }
    }
}

// ---------------- per-edge attention logits ----------------
// one wave per edge; lane covers 4 contiguous channels; lanes 0-31 = head0, 32-63 = head1
__global__ void edge_alpha(const float* __restrict__ xl, const float* __restrict__ xr,
                           const float* __restrict__ We, const float* __restrict__ att,
                           const float* __restrict__ ew, const int* __restrict__ src,
                           const int* __restrict__ dst, float* __restrict__ alpha) {
    int e = blockIdx.x * 4 + (threadIdx.x >> 6);
    int lane = threadIdx.x & 63;
    if (e >= N_EDGES) return;
    int s = src[e], d = dst[e];
    float w = ew[e];
    float4 l4 = *(const float4*)(xl + s*256 + lane*4);
    float4 r4 = *(const float4*)(xr + d*256 + lane*4);
    float4 w4 = *(const float4*)(We + lane*4);
    float4 a4 = *(const float4*)(att + lane*4);
    float v, sum = 0.f;
    v = l4.x + r4.x + w*w4.x; v = v > 0.f ? v : NEG_SLOPE*v; sum += v*a4.x;
    v = l4.y + r4.y + w*w4.y; v = v > 0.f ? v : NEG_SLOPE*v; sum += v*a4.y;
    v = l4.z + r4.z + w*w4.z; v = v > 0.f ? v : NEG_SLOPE*v; sum += v*a4.z;
    v = l4.w + r4.w + w*w4.w; v = v > 0.f ? v : NEG_SLOPE*v; sum += v*a4.w;
    #pragma unroll
    for (int m = 1; m <= 16; m <<= 1) sum += __shfl_xor(sum, m, 64);
    if ((lane & 31) == 0) alpha[e*2 + (lane >> 5)] = sum;
}

// ---------------- per-node softmax + aggregation (concat=True, +bias) ----------------
__global__ void aggregate_concat(const float* __restrict__ xl, const float* __restrict__ alpha,
                                 const int* __restrict__ offsets, const int* __restrict__ perm,
                                 const int* __restrict__ src, const float* __restrict__ bias,
                                 float* __restrict__ out) {
    int n = blockIdx.x * 4 + (threadIdx.x >> 6);
    int lane = threadIdx.x & 63;
    if (n >= N_NODES) return;
    int hh = lane >> 5;
    int beg = offsets[n], end = offsets[n+1];
    float m = -INFINITY;
    for (int i = beg; i < end; i++) {
        int e = perm[i];
        m = fmaxf(m, alpha[e*2 + hh]);
    }
    float den = 0.f;
    float ax = 0.f, ay = 0.f, az = 0.f, aw = 0.f;
    for (int i = beg; i < end; i++) {
        int e = perm[i];
        float a = __expf(alpha[e*2 + hh] - m);
        den += a;
        int s = src[e];
        float4 v = *(const float4*)(xl + s*256 + lane*4);
        ax += a*v.x; ay += a*v.y; az += a*v.z; aw += a*v.w;
    }
    float inv = 1.f / (den + 1e-16f);
    float4 b4 = *(const float4*)(bias + lane*4);
    float4 o;
    o.x = ax*inv + b4.x; o.y = ay*inv + b4.y; o.z = az*inv + b4.z; o.w = aw*inv + b4.w;
    *(float4*)(out + n*256 + lane*4) = o;
}

// ---------------- per-node softmax + aggregation (concat=False: mean over heads, +bias) ----------------
__global__ void aggregate_mean(const float* __restrict__ xl, const float* __restrict__ alpha,
                               const int* __restrict__ offsets, const int* __restrict__ perm,
                               const int* __restrict__ src, const float* __restrict__ bias,
                               float* __restrict__ out) {
    int n = blockIdx.x * 4 + (threadIdx.x >> 6);
    int lane = threadIdx.x & 63;
    if (n >= N_NODES) return;
    int hh = lane >> 5;
    int beg = offsets[n], end = offsets[n+1];
    float m = -INFINITY;
    for (int i = beg; i < end; i++) {
        int e = perm[i];
        m = fmaxf(m, alpha[e*2 + hh]);
    }
    float den = 0.f;
    float ax = 0.f, ay = 0.f, az = 0.f, aw = 0.f;
    for (int i = beg; i < end; i++) {
        int e = perm[i];
        float a = __expf(alpha[e*2 + hh] - m);
        den += a;
        int s = src[e];
        float4 v = *(const float4*)(xl + s*256 + lane*4);
        ax += a*v.x; ay += a*v.y; az += a*v.z; aw += a*v.w;
    }
    float inv = 1.f / (den + 1e-16f);
    float ox = ax*inv, oy = ay*inv, oz = az*inv, ow = aw*inv;
    // head1 partner is lane+32 (same channel within head)
    float px = __shfl_xor(ox, 32, 64);
    float py = __shfl_xor(oy, 32, 64);
    float pz = __shfl_xor(oz, 32, 64);
    float pw = __shfl_xor(ow, 32, 64);
    if (lane < 32) {
        float4 b4 = *(const float4*)(bias + lane*4);
        float4 o;
        o.x = (ox + px)*0.5f + b4.x;
        o.y = (oy + py)*0.5f + b4.y;
        o.z = (oz + pz)*0.5f + b4.z;
        o.w = (ow + pw)*0.5f + b4.w;
        *(float4*)(out + n*128 + lane*4) = o;
    }
}

// ---------------- BN1 over [N,256] + ReLU ----------------
__global__ void bn1_reduce(const float* __restrict__ x, float* __restrict__ sum,
                           float* __restrict__ sumsq) {
    int c = threadIdx.x;
    int r0 = blockIdx.x * 196;
    int r1 = r0 + 196; if (r1 > N_NODES) r1 = N_NODES;
    float s = 0.f, q = 0.f;
    for (int r = r0; r < r1; r++) {
        float v = x[r*256 + c];
        s += v; q += v*v;
    }
    atomicAdd(&sum[c], s);
    atomicAdd(&sumsq[c], q);
}

__global__ void bn1_apply_relu(float* __restrict__ x, const float* __restrict__ sum,
                               const float* __restrict__ sumsq, const float* __restrict__ g,
                               const float* __restrict__ b) {
    int i = blockIdx.x * 256 + threadIdx.x;
    int c = i & 255;
    float mean = sum[c] * (1.f / N_NODES);
    float var  = sumsq[c] * (1.f / N_NODES) - mean*mean;
    float sc = g[c] * rsqrtf(var + BN_EPS);
    float v = (x[i] - mean) * sc + b[c];
    x[i] = v > 0.f ? v : 0.f;
}

extern "C" void kernel_launch(void* const* d_in, const int* in_sizes, int n_in,
                              void* d_out, int out_size, void* d_ws, size_t ws_size,
                              hipStream_t stream) {
    const float* h          = (const float*)d_in[0];
    const int*   edge_index = (const int*)d_in[1];
    const int*   src = edge_index;
    const int*   dst = edge_index + N_EDGES;
    const float* ew   = (const float*)d_in[2];
    const float* bn0g = (const float*)d_in[3];
    const float* bn0b = (const float*)d_in[4];
    const float* bn1g = (const float*)d_in[5];
    const float* bn1b = (const float*)d_in[6];
    const float* c1_Wl = (const float*)d_in[7];
    const float* c1_bl = (const float*)d_in[8];
    const float* c1_Wr = (const float*)d_in[9];
    const float* c1_br = (const float*)d_in[10];
    const float* c1_We = (const float*)d_in[11];
    const float* c1_att = (const float*)d_in[12];
    const float* c1_bias = (const float*)d_in[13];
    const float* mu_Wl = (const float*)d_in[14];
    const float* mu_bl = (const float*)d_in[15];
    const float* mu_Wr = (const float*)d_in[16];
    const float* mu_br = (const float*)d_in[17];
    const float* mu_We = (const float*)d_in[18];
    const float* mu_att = (const float*)d_in[19];
    const float* mu_bias = (const float*)d_in[20];
    const float* ls_Wl = (const float*)d_in[21];
    const float* ls_bl = (const float*)d_in[22];
    const float* ls_Wr = (const float*)d_in[23];
    const float* ls_br = (const float*)d_in[24];
    const float* ls_We = (const float*)d_in[25];
    const float* ls_att = (const float*)d_in[26];
    const float* ls_bias = (const float*)d_in[27];

    float* out_mu = (float*)d_out;
    float* out_ls = (float*)d_out + (size_t)N_NODES * 128;

    // workspace carve-up (256B aligned blocks); total ~186 MB
    char* ws = (char*)d_ws;
    size_t off = 0;
    auto alloc = [&](size_t bytes) -> void* {
        void* p = ws + off;
        off += (bytes + 255) / 256 * 256;
        return p;
    };
    float* x0      = (float*)alloc((size_t)N_NODES * 5 * 4);
    float* xl      = (float*)alloc((size_t)N_NODES * 256 * 4);
    float* xr      = (float*)alloc((size_t)N_NODES * 256 * 4);
    float* xB      = (float*)alloc((size_t)N_NODES * 256 * 4);
    float* alpha   = (float*)alloc((size_t)N_EDGES * 2 * 4);
    float* bn0acc  = (float*)alloc(10 * 4);
    float* bn0ss   = (float*)alloc(10 * 4);
    float* bn1sum  = (float*)alloc(256 * 4);
    float* bn1sq   = (float*)alloc(256 * 4);
    int*   count   = (int*)alloc((size_t)N_NODES * 4);
    int*   offsets = (int*)alloc((size_t)(N_NODES + 1) * 4);
    int*   cursor  = (int*)alloc((size_t)N_NODES * 4);
    int*   perm    = (int*)alloc((size_t)N_EDGES * 4);
    int*   tileSum = (int*)alloc((size_t)SCAN_TILES * 4);
    int*   tilePre = (int*)alloc((size_t)SCAN_TILES * 4);
    unsigned short* Apack = (unsigned short*)alloc((size_t)RB_COUNT * 4096 * 2);  // 25.6 MB
    unsigned short* Bpack = (unsigned short*)alloc((size_t)2 * 131072 * 2);       // 512 KB

    hipMemsetAsync(count, 0, (size_t)N_NODES * 4, stream);
    hipMemsetAsync(bn0acc, 0, 10 * 4, stream);
    hipMemsetAsync(bn1sum, 0, 256 * 4, stream);
    hipMemsetAsync(bn1sq, 0, 256 * 4, stream);

    // BN0 (grid-parallel)
    bn0_reduce<<<128, 256, 0, stream>>>(h, bn0acc);
    bn0_finalize<<<1, 64, 0, stream>>>(bn0acc, bn0g, bn0b, bn0ss);
    bn0_apply<<<(N_NODES * 5 + 255) / 256, 256, 0, stream>>>(h, bn0ss, x0);

    // CSR by dst (shared by all 3 convs) — two-level parallel scan
    edge_count<<<(N_EDGES + 255) / 256, 256, 0, stream>>>(dst, count);
    local_scan<<<SCAN_TILES, 1024, 0, stream>>>(count, offsets, tileSum);
    tile_scan<<<1, 64, 0, stream>>>(tileSum, tilePre, offsets);
    add_prefix<<<SCAN_TILES, 1024, 0, stream>>>(offsets, tilePre, cursor);
    edge_scatter<<<(N_EDGES + 255) / 256, 256, 0, stream>>>(dst, cursor, perm);

    // pack mu/ls weights to bf16 fragment order (independent of graph data)
    pack_w<<<128, 256, 0, stream>>>(mu_Wl, mu_Wr, ls_Wl, ls_Wr, Bpack);

    // conv1 (concat)
    gemm_k5<<<N_NODES, 256, 0, stream>>>(x0, c1_Wl, c1_bl, c1_Wr, c1_br, xl, xr);
    edge_alpha<<<N_EDGES / 4, 256, 0, stream>>>(xl, xr, c1_We, c1_att, ew, src, dst, alpha);
    aggregate_concat<<<N_NODES / 4 + 1, 256, 0, stream>>>(xl, alpha, offsets, perm, src, c1_bias, xB);

    // BN1 + ReLU
    bn1_reduce<<<256, 256, 0, stream>>>(xB, bn1sum, bn1sq);
    bn1_apply_relu<<<N_NODES, 256, 0, stream>>>(xB, bn1sum, bn1sq, bn1g, bn1b);

    // pack activations once (mu and ls share the same input)
    pack_x<<<6256, 256, 0, stream>>>(xB, Apack);

    // mu conv (head-mean)
    gemm_mfma<<<782, 512, 0, stream>>>(Apack, Bpack, mu_bl, mu_br, xl, xr);
    edge_alpha<<<N_EDGES / 4, 256, 0, stream>>>(xl, xr, mu_We, mu_att, ew, src, dst, alpha);
    aggregate_mean<<<N_NODES / 4 + 1, 256, 0, stream>>>(xl, alpha, offsets, perm, src, mu_bias, out_mu);

    // log_std conv (head-mean)
    gemm_mfma<<<782, 512, 0, stream>>>(Apack, Bpack + 131072, ls_bl, ls_br, xl, xr);
    edge_alpha<<<N_EDGES / 4, 256, 0, stream>>>(xl, xr, ls_We, ls_att, ew, src, dst, alpha);
    aggregate_mean<<<N_NODES / 4 + 1, 256, 0, stream>>>(xl, alpha, offsets, perm, src, ls_bias, out_ls);
}

// Round 4
// 558.776 us; speedup vs baseline: 2.4720x; 1.5927x over previous
//
#include <hip/hip_runtime.h>
#include <math.h>

#define N_NODES 50000
#define N_EDGES 300000
#define BN_EPS 1e-5f
#define NEG_SLOPE 0.2f

// 50000 rows pad to 3128 row-blocks of 16 (50048)
#define RB_COUNT 3128
#define SCAN_TILES 49   // 49*1024 = 50176 >= N_NODES

typedef short bf8v __attribute__((ext_vector_type(8)));
typedef float f4v __attribute__((ext_vector_type(4)));

__device__ inline unsigned short f2bf(float f) {
    union { float f; unsigned u; } c; c.f = f;
    unsigned r = c.u + 0x7fffu + ((c.u >> 16) & 1u);
    return (unsigned short)(r >> 16);
}
__device__ inline float bf2f(unsigned short u) {
    union { unsigned u; float f; } c; c.u = ((unsigned)u) << 16;
    return c.f;
}

// ---------------- BN0 (5 columns), grid-parallel ----------------
__global__ void bn0_reduce(const float* __restrict__ h, float* __restrict__ acc /*[10]*/) {
    __shared__ float lds[4][10];
    int tid = threadIdx.x;
    int lane = tid & 63, wave = tid >> 6;
    float ls[5] = {0,0,0,0,0}, lq[5] = {0,0,0,0,0};
    for (int r = blockIdx.x * 256 + tid; r < N_NODES; r += 128 * 256) {
        #pragma unroll
        for (int k = 0; k < 5; k++) {
            float v = h[r*5 + k];
            ls[k] += v; lq[k] += v*v;
        }
    }
    #pragma unroll
    for (int k = 0; k < 5; k++) {
        #pragma unroll
        for (int m = 1; m <= 32; m <<= 1) {
            ls[k] += __shfl_xor(ls[k], m, 64);
            lq[k] += __shfl_xor(lq[k], m, 64);
        }
    }
    if (lane == 0) {
        #pragma unroll
        for (int k = 0; k < 5; k++) { lds[wave][k] = ls[k]; lds[wave][5+k] = lq[k]; }
    }
    __syncthreads();
    if (tid < 10) {
        float s = lds[0][tid] + lds[1][tid] + lds[2][tid] + lds[3][tid];
        atomicAdd(&acc[tid], s);
    }
}

__global__ void bn0_finalize(const float* __restrict__ acc, const float* __restrict__ g,
                             const float* __restrict__ b, float* __restrict__ ss) {
    int tid = threadIdx.x;
    if (tid < 5) {
        float mean = acc[tid] * (1.f / N_NODES);
        float var  = acc[5 + tid] * (1.f / N_NODES) - mean*mean;
        float sc = g[tid] * rsqrtf(var + BN_EPS);
        ss[tid]     = sc;
        ss[5 + tid] = b[tid] - mean * sc;
    }
}

__global__ void bn0_apply(const float* __restrict__ h, const float* __restrict__ ss,
                          float* __restrict__ x0) {
    int i = blockIdx.x * blockDim.x + threadIdx.x;
    if (i < N_NODES * 5) {
        int k = i % 5;
        x0[i] = h[i] * ss[k] + ss[5 + k];
    }
}

// ---------------- CSR build by dst ----------------
__global__ void edge_count(const int* __restrict__ dst, int* __restrict__ count) {
    int e = blockIdx.x * blockDim.x + threadIdx.x;
    if (e < N_EDGES) atomicAdd(&count[dst[e]], 1);
}

// two-level scan: per-tile local exclusive scan + tile totals
__global__ void local_scan(const int* __restrict__ count, int* __restrict__ offsets,
                           int* __restrict__ tileSum) {
    __shared__ int lds[1024];
    int tid = threadIdx.x;
    int i = blockIdx.x * 1024 + tid;
    int v = (i < N_NODES) ? count[i] : 0;
    lds[tid] = v;
    __syncthreads();
    #pragma unroll
    for (int off = 1; off < 1024; off <<= 1) {
        int t = (tid >= off) ? lds[tid - off] : 0;
        __syncthreads();
        lds[tid] += t;
        __syncthreads();
    }
    if (i < N_NODES) offsets[i] = lds[tid] - v;   // local exclusive
    if (tid == 1023) tileSum[blockIdx.x] = lds[1023];
}

__global__ void tile_scan(const int* __restrict__ tileSum, int* __restrict__ tilePrefix,
                          int* __restrict__ offsets) {
    int lane = threadIdx.x;
    int v = (lane < SCAN_TILES) ? tileSum[lane] : 0;
    int inc = v;
    #pragma unroll
    for (int off = 1; off < 64; off <<= 1) {
        int t = __shfl_up(inc, off, 64);
        if (lane >= off) inc += t;
    }
    int excl = inc - v;
    if (lane < SCAN_TILES) tilePrefix[lane] = excl;
    if (lane == SCAN_TILES - 1) offsets[N_NODES] = inc;
}

__global__ void add_prefix(int* __restrict__ offsets, const int* __restrict__ tilePrefix,
                           int* __restrict__ cursor) {
    int i = blockIdx.x * 1024 + threadIdx.x;
    if (i < N_NODES) {
        int o = offsets[i] + tilePrefix[blockIdx.x];
        offsets[i] = o;
        cursor[i] = o;
    }
}

// scatter edge ids into CSR order; also materialize src and edge-weight in CSR order
__global__ void edge_scatter(const int* __restrict__ dst, const int* __restrict__ src,
                             const float* __restrict__ ew, int* __restrict__ cursor,
                             int* __restrict__ srcp, float* __restrict__ ewp) {
    int e = blockIdx.x * blockDim.x + threadIdx.x;
    if (e < N_EDGES) {
        int pos = atomicAdd(&cursor[dst[e]], 1);
        srcp[pos] = src[e];
        ewp[pos] = ew[e];
    }
}

// ---------------- conv1 linear (K=5), bf16 output ----------------
__global__ void gemm_k5(const float* __restrict__ x0,
                        const float* __restrict__ Wl, const float* __restrict__ bl,
                        const float* __restrict__ Wr, const float* __restrict__ br,
                        unsigned short* __restrict__ xl, unsigned short* __restrict__ xr) {
    int n = blockIdx.x;
    int c = threadIdx.x;
    float a0 = x0[n*5+0], a1 = x0[n*5+1], a2 = x0[n*5+2], a3 = x0[n*5+3], a4 = x0[n*5+4];
    float l = bl[c] + a0*Wl[c] + a1*Wl[256+c] + a2*Wl[512+c] + a3*Wl[768+c] + a4*Wl[1024+c];
    float r = br[c] + a0*Wr[c] + a1*Wr[256+c] + a2*Wr[512+c] + a3*Wr[768+c] + a4*Wr[1024+c];
    xl[n*256 + c] = f2bf(l);
    xr[n*256 + c] = f2bf(r);
}

// ---------------- pack X with fused BN1+ReLU (fp32 xB -> bf16 MFMA A-fragment order) ----
// layout: [rb][kc][lane][j], elem = relu(bn(X[rb*16 + (lane&15)][kc*32 + (lane>>4)*8 + j]))
__global__ void pack_x_bn(const float* __restrict__ x,
                          const float* __restrict__ sum, const float* __restrict__ sumsq,
                          const float* __restrict__ g, const float* __restrict__ b,
                          unsigned short* __restrict__ ap) {
    int t = blockIdx.x * 256 + threadIdx.x;   // RB_COUNT*8*64 = 1601536 threads exact
    int lane = t & 63;
    int kc = (t >> 6) & 7;
    int rb = t >> 9;
    int row = rb * 16 + (lane & 15);
    int k0 = kc * 32 + (lane >> 4) * 8;
    union { unsigned short h[8]; uint4 u; } tmp;
    if (row < N_NODES) {
        const float* s = x + (size_t)row * 256 + k0;
        #pragma unroll
        for (int j = 0; j < 8; j++) {
            int c = k0 + j;
            float mean = sum[c] * (1.f / N_NODES);
            float var  = sumsq[c] * (1.f / N_NODES) - mean*mean;
            float sc = g[c] * rsqrtf(var + BN_EPS);
            float v = (s[j] - mean) * sc + b[c];
            v = v > 0.f ? v : 0.f;
            tmp.h[j] = f2bf(v);
        }
    } else {
        #pragma unroll
        for (int j = 0; j < 8; j++) tmp.h[j] = 0;
    }
    *reinterpret_cast<uint4*>(ap + (size_t)t * 8) = tmp.u;
}

// ---------------- pack W for both convs (fp32 -> bf16 MFMA B-fragment order) ----------------
__global__ void pack_w(const float* __restrict__ Wl0, const float* __restrict__ Wr0,
                       const float* __restrict__ Wl1, const float* __restrict__ Wr1,
                       unsigned short* __restrict__ bp) {
    int t = blockIdx.x * 256 + threadIdx.x;   // 2*8*32*64 = 32768 threads exact
    int lane = t & 63;
    int nt = (t >> 6) & 31;
    int kc = (t >> 11) & 7;
    int conv = t >> 14;
    int col = nt * 16 + (lane & 15);
    int k0 = kc * 32 + (lane >> 4) * 8;
    const float* W = conv ? (col < 256 ? Wl1 : Wr1) : (col < 256 ? Wl0 : Wr0);
    int c = col & 255;
    union { unsigned short h[8]; uint4 u; } tmp;
    #pragma unroll
    for (int j = 0; j < 8; j++) tmp.h[j] = f2bf(W[(size_t)(k0 + j) * 256 + c]);
    *reinterpret_cast<uint4*>(bp + (size_t)t * 8) = tmp.u;
}

// ---------------- big linear via MFMA, bf16 output ----------------
__global__ __launch_bounds__(512) void gemm_mfma(const unsigned short* __restrict__ ap,
        const unsigned short* __restrict__ bp,
        const float* __restrict__ bl, const float* __restrict__ br,
        unsigned short* __restrict__ xl, unsigned short* __restrict__ xr) {
    int lane = threadIdx.x & 63;
    int wave = threadIdx.x >> 6;
    int h = wave & 1;
    int rb = blockIdx.x * 4 + (wave >> 1);
    f4v acc[16];
    #pragma unroll
    for (int t = 0; t < 16; t++) acc[t] = (f4v){0.f, 0.f, 0.f, 0.f};
    const unsigned short* aptr = ap + (size_t)rb * 4096 + lane * 8;
    const unsigned short* bptr = bp + (size_t)h * 8192 + lane * 8;
    for (int kc = 0; kc < 8; kc++) {
        bf8v a = *reinterpret_cast<const bf8v*>(aptr + kc * 512);
        const unsigned short* bb = bptr + (size_t)kc * 16384;
        #pragma unroll
        for (int t = 0; t < 16; t++) {
            bf8v b = *reinterpret_cast<const bf8v*>(bb + t * 512);
            acc[t] = __builtin_amdgcn_mfma_f32_16x16x32_bf16(a, b, acc[t], 0, 0, 0);
        }
    }
    int c15 = lane & 15;
    int row0 = rb * 16 + (lane >> 4) * 4;
    unsigned short* outp = h ? xr : xl;
    const float* bias = h ? br : bl;
    #pragma unroll
    for (int t = 0; t < 16; t++) {
        int col = t * 16 + c15;
        float bv = bias[col];
        #pragma unroll
        for (int r = 0; r < 4; r++) {
            int row = row0 + r;
            if (row < N_NODES) outp[(size_t)row * 256 + col] = f2bf(acc[t][r] + bv);
        }
    }
}

// ---------------- fused GATv2 edge phase: alpha + online-softmax + aggregate ----------
// one wave per node; lane: head = lane>>5, 4 channels = (lane&31)*4 within head.
// xl/xr in bf16. CONCAT: write 256-ch fp32 out. MEAN: head-average, 128-ch fp32 out.
template <int CONCAT>
__global__ void agg_fused(const unsigned short* __restrict__ xl,
                          const unsigned short* __restrict__ xr,
                          const float* __restrict__ We, const float* __restrict__ att,
                          const int* __restrict__ offsets, const int* __restrict__ srcp,
                          const float* __restrict__ ewp, const float* __restrict__ bias,
                          float* __restrict__ out) {
    int n = blockIdx.x * 4 + (threadIdx.x >> 6);
    int lane = threadIdx.x & 63;
    if (n >= N_NODES) return;
    int col = (lane >> 5) * 128 + (lane & 31) * 4;   // channel base in [0,256)
    float4 w4 = *(const float4*)(We + col);
    float4 a4 = *(const float4*)(att + col);
    ushort4 r4 = *(const ushort4*)(xr + (size_t)n * 256 + col);
    float rx = bf2f(r4.x), ry = bf2f(r4.y), rz = bf2f(r4.z), rw = bf2f(r4.w);
    int beg = offsets[n], end = offsets[n + 1];
    float mrun = -INFINITY, den = 0.f;
    float ax = 0.f, ay = 0.f, az = 0.f, aw = 0.f;
    for (int i = beg; i < end; i++) {
        int s = srcp[i];
        float w = ewp[i];
        ushort4 l4 = *(const ushort4*)(xl + (size_t)s * 256 + col);
        float lx = bf2f(l4.x), ly = bf2f(l4.y), lz = bf2f(l4.z), lw = bf2f(l4.w);
        float v, a = 0.f;
        v = lx + rx + w*w4.x; v = v > 0.f ? v : NEG_SLOPE*v; a += v*a4.x;
        v = ly + ry + w*w4.y; v = v > 0.f ? v : NEG_SLOPE*v; a += v*a4.y;
        v = lz + rz + w*w4.z; v = v > 0.f ? v : NEG_SLOPE*v; a += v*a4.z;
        v = lw + rw + w*w4.w; v = v > 0.f ? v : NEG_SLOPE*v; a += v*a4.w;
        #pragma unroll
        for (int mm = 1; mm <= 16; mm <<= 1) a += __shfl_xor(a, mm, 64);
        float nm = fmaxf(mrun, a);
        float sc = __expf(mrun - nm);   // first iter: exp(-inf)=0
        float p  = __expf(a - nm);
        den = den * sc + p;
        ax = ax * sc + p * lx;
        ay = ay * sc + p * ly;
        az = az * sc + p * lz;
        aw = aw * sc + p * lw;
        mrun = nm;
    }
    float inv = 1.f / (den + 1e-16f);
    if (CONCAT) {
        float4 b4 = *(const float4*)(bias + col);
        float4 o;
        o.x = ax*inv + b4.x; o.y = ay*inv + b4.y; o.z = az*inv + b4.z; o.w = aw*inv + b4.w;
        *(float4*)(out + (size_t)n * 256 + col) = o;
    } else {
        float ox = ax*inv, oy = ay*inv, oz = az*inv, ow = aw*inv;
        float px = __shfl_xor(ox, 32, 64);
        float py = __shfl_xor(oy, 32, 64);
        float pz = __shfl_xor(oz, 32, 64);
        float pw = __shfl_xor(ow, 32, 64);
        if (lane < 32) {
            float4 b4 = *(const float4*)(bias + lane * 4);
            float4 o;
            o.x = (ox + px)*0.5f + b4.x;
            o.y = (oy + py)*0.5f + b4.y;
            o.z = (oz + pz)*0.5f + b4.z;
            o.w = (ow + pw)*0.5f + b4.w;
            *(float4*)(out + (size_t)n * 128 + lane * 4) = o;
        }
    }
}

// ---------------- BN1 stats over [N,256] ----------------
__global__ void bn1_reduce(const float* __restrict__ x, float* __restrict__ sum,
                           float* __restrict__ sumsq) {
    int c = threadIdx.x;
    int r0 = blockIdx.x * 196;
    int r1 = r0 + 196; if (r1 > N_NODES) r1 = N_NODES;
    float s = 0.f, q = 0.f;
    for (int r = r0; r < r1; r++) {
        float v = x[r*256 + c];
        s += v; q += v*v;
    }
    atomicAdd(&sum[c], s);
    atomicAdd(&sumsq[c], q);
}

extern "C" void kernel_launch(void* const* d_in, const int* in_sizes, int n_in,
                              void* d_out, int out_size, void* d_ws, size_t ws_size,
                              hipStream_t stream) {
    const float* h          = (const float*)d_in[0];
    const int*   edge_index = (const int*)d_in[1];
    const int*   src = edge_index;
    const int*   dst = edge_index + N_EDGES;
    const float* ew   = (const float*)d_in[2];
    const float* bn0g = (const float*)d_in[3];
    const float* bn0b = (const float*)d_in[4];
    const float* bn1g = (const float*)d_in[5];
    const float* bn1b = (const float*)d_in[6];
    const float* c1_Wl = (const float*)d_in[7];
    const float* c1_bl = (const float*)d_in[8];
    const float* c1_Wr = (const float*)d_in[9];
    const float* c1_br = (const float*)d_in[10];
    const float* c1_We = (const float*)d_in[11];
    const float* c1_att = (const float*)d_in[12];
    const float* c1_bias = (const float*)d_in[13];
    const float* mu_Wl = (const float*)d_in[14];
    const float* mu_bl = (const float*)d_in[15];
    const float* mu_Wr = (const float*)d_in[16];
    const float* mu_br = (const float*)d_in[17];
    const float* mu_We = (const float*)d_in[18];
    const float* mu_att = (const float*)d_in[19];
    const float* mu_bias = (const float*)d_in[20];
    const float* ls_Wl = (const float*)d_in[21];
    const float* ls_bl = (const float*)d_in[22];
    const float* ls_Wr = (const float*)d_in[23];
    const float* ls_br = (const float*)d_in[24];
    const float* ls_We = (const float*)d_in[25];
    const float* ls_att = (const float*)d_in[26];
    const float* ls_bias = (const float*)d_in[27];

    float* out_mu = (float*)d_out;
    float* out_ls = (float*)d_out + (size_t)N_NODES * 128;

    // workspace carve-up (256B aligned blocks)
    char* ws = (char*)d_ws;
    size_t off = 0;
    auto alloc = [&](size_t bytes) -> void* {
        void* p = ws + off;
        off += (bytes + 255) / 256 * 256;
        return p;
    };
    float* x0      = (float*)alloc((size_t)N_NODES * 5 * 4);
    unsigned short* xl = (unsigned short*)alloc((size_t)N_NODES * 256 * 2);
    unsigned short* xr = (unsigned short*)alloc((size_t)N_NODES * 256 * 2);
    float* xB      = (float*)alloc((size_t)N_NODES * 256 * 4);
    float* bn0acc  = (float*)alloc(10 * 4);
    float* bn0ss   = (float*)alloc(10 * 4);
    float* bn1sum  = (float*)alloc(256 * 4);
    float* bn1sq   = (float*)alloc(256 * 4);
    int*   count   = (int*)alloc((size_t)N_NODES * 4);
    int*   offsets = (int*)alloc((size_t)(N_NODES + 1) * 4);
    int*   cursor  = (int*)alloc((size_t)N_NODES * 4);
    int*   srcp    = (int*)alloc((size_t)N_EDGES * 4);
    float* ewp     = (float*)alloc((size_t)N_EDGES * 4);
    int*   tileSum = (int*)alloc((size_t)SCAN_TILES * 4);
    int*   tilePre = (int*)alloc((size_t)SCAN_TILES * 4);
    unsigned short* Apack = (unsigned short*)alloc((size_t)RB_COUNT * 4096 * 2);  // 25.6 MB
    unsigned short* Bpack = (unsigned short*)alloc((size_t)2 * 131072 * 2);       // 512 KB

    hipMemsetAsync(count, 0, (size_t)N_NODES * 4, stream);
    hipMemsetAsync(bn0acc, 0, 10 * 4, stream);
    hipMemsetAsync(bn1sum, 0, 256 * 4, stream);
    hipMemsetAsync(bn1sq, 0, 256 * 4, stream);

    // BN0 (grid-parallel)
    bn0_reduce<<<128, 256, 0, stream>>>(h, bn0acc);
    bn0_finalize<<<1, 64, 0, stream>>>(bn0acc, bn0g, bn0b, bn0ss);
    bn0_apply<<<(N_NODES * 5 + 255) / 256, 256, 0, stream>>>(h, bn0ss, x0);

    // CSR by dst (shared by all 3 convs) — two-level parallel scan
    edge_count<<<(N_EDGES + 255) / 256, 256, 0, stream>>>(dst, count);
    local_scan<<<SCAN_TILES, 1024, 0, stream>>>(count, offsets, tileSum);
    tile_scan<<<1, 64, 0, stream>>>(tileSum, tilePre, offsets);
    add_prefix<<<SCAN_TILES, 1024, 0, stream>>>(offsets, tilePre, cursor);
    edge_scatter<<<(N_EDGES + 255) / 256, 256, 0, stream>>>(dst, src, ew, cursor, srcp, ewp);

    // pack mu/ls weights to bf16 fragment order
    pack_w<<<128, 256, 0, stream>>>(mu_Wl, mu_Wr, ls_Wl, ls_Wr, Bpack);

    // conv1 (concat)
    gemm_k5<<<N_NODES, 256, 0, stream>>>(x0, c1_Wl, c1_bl, c1_Wr, c1_br, xl, xr);
    agg_fused<1><<<N_NODES / 4 + 1, 256, 0, stream>>>(xl, xr, c1_We, c1_att, offsets,
                                                      srcp, ewp, c1_bias, xB);

    // BN1 stats; apply+ReLU fused into pack
    bn1_reduce<<<256, 256, 0, stream>>>(xB, bn1sum, bn1sq);
    pack_x_bn<<<6256, 256, 0, stream>>>(xB, bn1sum, bn1sq, bn1g, bn1b, Apack);

    // mu conv (head-mean)
    gemm_mfma<<<782, 512, 0, stream>>>(Apack, Bpack, mu_bl, mu_br, xl, xr);
    agg_fused<0><<<N_NODES / 4 + 1, 256, 0, stream>>>(xl, xr, mu_We, mu_att, offsets,
                                                      srcp, ewp, mu_bias, out_mu);

    // log_std conv (head-mean)
    gemm_mfma<<<782, 512, 0, stream>>>(Apack, Bpack + 131072, ls_bl, ls_br, xl, xr);
    agg_fused<0><<<N_NODES / 4 + 1, 256, 0, stream>>>(xl, xr, ls_We, ls_att, offsets,
                                                      srcp, ewp, ls_bias, out_ls);
}

// Round 5
// 511.351 us; speedup vs baseline: 2.7013x; 1.0927x over previous
//
#include <hip/hip_runtime.h>
#include <math.h>

#define N_NODES 50000
#define N_EDGES 300000
#define BN_EPS 1e-5f
#define NEG_SLOPE 0.2f

// 50000 rows pad to 3128 row-blocks of 16 (50048)
#define RB_COUNT 3128
#define SCAN_TILES 49   // 49*1024 = 50176 >= N_NODES

typedef short bf8v __attribute__((ext_vector_type(8)));
typedef float f4v __attribute__((ext_vector_type(4)));

__device__ inline unsigned short f2bf(float f) {
    union { float f; unsigned u; } c; c.f = f;
    unsigned r = c.u + 0x7fffu + ((c.u >> 16) & 1u);
    return (unsigned short)(r >> 16);
}
__device__ inline float bf2f(unsigned short u) {
    union { unsigned u; float f; } c; c.u = ((unsigned)u) << 16;
    return c.f;
}

// async global->LDS DMA, 16B per lane; LDS dest = ldsbase + lane*16 (wave-uniform base)
__device__ inline void async_copy16(void* lds, const void* g) {
    __builtin_amdgcn_global_load_lds(
        (const __attribute__((address_space(1))) unsigned int*)g,
        (__attribute__((address_space(3))) unsigned int*)lds, 16, 0, 0);
}

// ---------------- BN0 (5 columns), grid-parallel ----------------
__global__ void bn0_reduce(const float* __restrict__ h, float* __restrict__ acc /*[10]*/) {
    __shared__ float lds[4][10];
    int tid = threadIdx.x;
    int lane = tid & 63, wave = tid >> 6;
    float ls[5] = {0,0,0,0,0}, lq[5] = {0,0,0,0,0};
    for (int r = blockIdx.x * 256 + tid; r < N_NODES; r += 128 * 256) {
        #pragma unroll
        for (int k = 0; k < 5; k++) {
            float v = h[r*5 + k];
            ls[k] += v; lq[k] += v*v;
        }
    }
    #pragma unroll
    for (int k = 0; k < 5; k++) {
        #pragma unroll
        for (int m = 1; m <= 32; m <<= 1) {
            ls[k] += __shfl_xor(ls[k], m, 64);
            lq[k] += __shfl_xor(lq[k], m, 64);
        }
    }
    if (lane == 0) {
        #pragma unroll
        for (int k = 0; k < 5; k++) { lds[wave][k] = ls[k]; lds[wave][5+k] = lq[k]; }
    }
    __syncthreads();
    if (tid < 10) {
        float s = lds[0][tid] + lds[1][tid] + lds[2][tid] + lds[3][tid];
        atomicAdd(&acc[tid], s);
    }
}

__global__ void bn0_finalize(const float* __restrict__ acc, const float* __restrict__ g,
                             const float* __restrict__ b, float* __restrict__ ss) {
    int tid = threadIdx.x;
    if (tid < 5) {
        float mean = acc[tid] * (1.f / N_NODES);
        float var  = acc[5 + tid] * (1.f / N_NODES) - mean*mean;
        float sc = g[tid] * rsqrtf(var + BN_EPS);
        ss[tid]     = sc;
        ss[5 + tid] = b[tid] - mean * sc;
    }
}

__global__ void bn0_apply(const float* __restrict__ h, const float* __restrict__ ss,
                          float* __restrict__ x0) {
    int i = blockIdx.x * blockDim.x + threadIdx.x;
    if (i < N_NODES * 5) {
        int k = i % 5;
        x0[i] = h[i] * ss[k] + ss[5 + k];
    }
}

// ---------------- CSR build by dst ----------------
__global__ void edge_count(const int* __restrict__ dst, int* __restrict__ count) {
    int e = blockIdx.x * blockDim.x + threadIdx.x;
    if (e < N_EDGES) atomicAdd(&count[dst[e]], 1);
}

// two-level scan: per-tile local exclusive scan + tile totals
__global__ void local_scan(const int* __restrict__ count, int* __restrict__ offsets,
                           int* __restrict__ tileSum) {
    __shared__ int lds[1024];
    int tid = threadIdx.x;
    int i = blockIdx.x * 1024 + tid;
    int v = (i < N_NODES) ? count[i] : 0;
    lds[tid] = v;
    __syncthreads();
    #pragma unroll
    for (int off = 1; off < 1024; off <<= 1) {
        int t = (tid >= off) ? lds[tid - off] : 0;
        __syncthreads();
        lds[tid] += t;
        __syncthreads();
    }
    if (i < N_NODES) offsets[i] = lds[tid] - v;   // local exclusive
    if (tid == 1023) tileSum[blockIdx.x] = lds[1023];
}

__global__ void tile_scan(const int* __restrict__ tileSum, int* __restrict__ tilePrefix,
                          int* __restrict__ offsets) {
    int lane = threadIdx.x;
    int v = (lane < SCAN_TILES) ? tileSum[lane] : 0;
    int inc = v;
    #pragma unroll
    for (int off = 1; off < 64; off <<= 1) {
        int t = __shfl_up(inc, off, 64);
        if (lane >= off) inc += t;
    }
    int excl = inc - v;
    if (lane < SCAN_TILES) tilePrefix[lane] = excl;
    if (lane == SCAN_TILES - 1) offsets[N_NODES] = inc;
}

__global__ void add_prefix(int* __restrict__ offsets, const int* __restrict__ tilePrefix,
                           int* __restrict__ cursor) {
    int i = blockIdx.x * 1024 + threadIdx.x;
    if (i < N_NODES) {
        int o = offsets[i] + tilePrefix[blockIdx.x];
        offsets[i] = o;
        cursor[i] = o;
    }
}

// scatter edge ids into CSR order; also materialize src and edge-weight in CSR order
__global__ void edge_scatter(const int* __restrict__ dst, const int* __restrict__ src,
                             const float* __restrict__ ew, int* __restrict__ cursor,
                             int* __restrict__ srcp, float* __restrict__ ewp) {
    int e = blockIdx.x * blockDim.x + threadIdx.x;
    if (e < N_EDGES) {
        int pos = atomicAdd(&cursor[dst[e]], 1);
        srcp[pos] = src[e];
        ewp[pos] = ew[e];
    }
}

// ---------------- conv1 linear (K=5), bf16 output ----------------
__global__ void gemm_k5(const float* __restrict__ x0,
                        const float* __restrict__ Wl, const float* __restrict__ bl,
                        const float* __restrict__ Wr, const float* __restrict__ br,
                        unsigned short* __restrict__ xl, unsigned short* __restrict__ xr) {
    int n = blockIdx.x;
    int c = threadIdx.x;
    float a0 = x0[n*5+0], a1 = x0[n*5+1], a2 = x0[n*5+2], a3 = x0[n*5+3], a4 = x0[n*5+4];
    float l = bl[c] + a0*Wl[c] + a1*Wl[256+c] + a2*Wl[512+c] + a3*Wl[768+c] + a4*Wl[1024+c];
    float r = br[c] + a0*Wr[c] + a1*Wr[256+c] + a2*Wr[512+c] + a3*Wr[768+c] + a4*Wr[1024+c];
    xl[n*256 + c] = f2bf(l);
    xr[n*256 + c] = f2bf(r);
}

// ---------------- pack X with fused BN1+ReLU (fp32 xB -> bf16 MFMA A-fragment order) ----
__global__ void pack_x_bn(const float* __restrict__ x,
                          const float* __restrict__ sum, const float* __restrict__ sumsq,
                          const float* __restrict__ g, const float* __restrict__ b,
                          unsigned short* __restrict__ ap) {
    int t = blockIdx.x * 256 + threadIdx.x;   // RB_COUNT*8*64 = 1601536 threads exact
    int lane = t & 63;
    int kc = (t >> 6) & 7;
    int rb = t >> 9;
    int row = rb * 16 + (lane & 15);
    int k0 = kc * 32 + (lane >> 4) * 8;
    union { unsigned short h[8]; uint4 u; } tmp;
    if (row < N_NODES) {
        const float* s = x + (size_t)row * 256 + k0;
        #pragma unroll
        for (int j = 0; j < 8; j++) {
            int c = k0 + j;
            float mean = sum[c] * (1.f / N_NODES);
            float var  = sumsq[c] * (1.f / N_NODES) - mean*mean;
            float sc = g[c] * rsqrtf(var + BN_EPS);
            float v = (s[j] - mean) * sc + b[c];
            v = v > 0.f ? v : 0.f;
            tmp.h[j] = f2bf(v);
        }
    } else {
        #pragma unroll
        for (int j = 0; j < 8; j++) tmp.h[j] = 0;
    }
    *reinterpret_cast<uint4*>(ap + (size_t)t * 8) = tmp.u;
}

// ---------------- pack W for both convs (fp32 -> bf16 MFMA B-fragment order) ----------------
__global__ void pack_w(const float* __restrict__ Wl0, const float* __restrict__ Wr0,
                       const float* __restrict__ Wl1, const float* __restrict__ Wr1,
                       unsigned short* __restrict__ bp) {
    int t = blockIdx.x * 256 + threadIdx.x;   // 2*8*32*64 = 32768 threads exact
    int lane = t & 63;
    int nt = (t >> 6) & 31;
    int kc = (t >> 11) & 7;
    int conv = t >> 14;
    int col = nt * 16 + (lane & 15);
    int k0 = kc * 32 + (lane >> 4) * 8;
    const float* W = conv ? (col < 256 ? Wl1 : Wr1) : (col < 256 ? Wl0 : Wr0);
    int c = col & 255;
    union { unsigned short h[8]; uint4 u; } tmp;
    #pragma unroll
    for (int j = 0; j < 8; j++) tmp.h[j] = f2bf(W[(size_t)(k0 + j) * 256 + c]);
    *reinterpret_cast<uint4*>(bp + (size_t)t * 8) = tmp.u;
}

// ---------------- big linear via MFMA, LDS-staged B (double-buffered), bf16 output -------
// block = 512 threads = 8 waves: wave>>1 = row-slice rb, wave&1 = col half h.
// B tile per kc = 32 frags (2h x 16t) x 1KB = 32KB; double buffered = 64KB LDS.
// Each wave DMAs 4 frags/kc via global_load_lds; A-frags preloaded to registers.
__global__ __launch_bounds__(512) void gemm_mfma(const unsigned short* __restrict__ ap,
        const unsigned short* __restrict__ bp,
        const float* __restrict__ bl, const float* __restrict__ br,
        unsigned short* __restrict__ xl, unsigned short* __restrict__ xr) {
    __shared__ unsigned short Bs[2][32][512];   // [buf][frag f=h*16+t][lane*8]
    int lane = threadIdx.x & 63;
    int wave = threadIdx.x >> 6;
    int h = wave & 1;
    int rb = blockIdx.x * 4 + (wave >> 1);

    const unsigned short* aptr = ap + (size_t)rb * 4096 + lane * 8;
    const unsigned short* bsrc = bp + lane * 8;

    // stage B[kc] into Bs[buf]: this wave's 4 frags (f = wave*4 + j; f -> offset f*512)
    auto stage = [&](int buf, int kc) {
        #pragma unroll
        for (int j = 0; j < 4; j++) {
            int f = wave * 4 + j;
            async_copy16(&Bs[buf][f][lane * 8], bsrc + (size_t)kc * 16384 + f * 512);
        }
    };
    stage(0, 0);

    // preload all A fragments (8 kc x 16B/lane = 32 VGPRs)
    bf8v a[8];
    #pragma unroll
    for (int kc = 0; kc < 8; kc++) a[kc] = *reinterpret_cast<const bf8v*>(aptr + kc * 512);

    f4v acc[16];
    #pragma unroll
    for (int t = 0; t < 16; t++) acc[t] = (f4v){0.f, 0.f, 0.f, 0.f};

    for (int kc = 0; kc < 8; kc++) {
        __syncthreads();                       // staging of buf kc&1 complete; prev buf free
        if (kc < 7) stage((kc + 1) & 1, kc + 1);
        const unsigned short* bb = &Bs[kc & 1][h * 16][lane * 8];
        #pragma unroll
        for (int t = 0; t < 16; t++) {
            bf8v b = *reinterpret_cast<const bf8v*>(bb + t * 512);
            acc[t] = __builtin_amdgcn_mfma_f32_16x16x32_bf16(a[kc], b, acc[t], 0, 0, 0);
        }
    }

    int c15 = lane & 15;
    int row0 = rb * 16 + (lane >> 4) * 4;
    unsigned short* outp = h ? xr : xl;
    const float* bias = h ? br : bl;
    #pragma unroll
    for (int t = 0; t < 16; t++) {
        int col = t * 16 + c15;
        float bv = bias[col];
        #pragma unroll
        for (int r = 0; r < 4; r++) {
            int row = row0 + r;
            if (row < N_NODES) outp[(size_t)row * 256 + col] = f2bf(acc[t][r] + bv);
        }
    }
}

// ---------------- fused GATv2 edge phase: alpha + online-softmax + aggregate ----------
template <int CONCAT>
__global__ void agg_fused(const unsigned short* __restrict__ xl,
                          const unsigned short* __restrict__ xr,
                          const float* __restrict__ We, const float* __restrict__ att,
                          const int* __restrict__ offsets, const int* __restrict__ srcp,
                          const float* __restrict__ ewp, const float* __restrict__ bias,
                          float* __restrict__ out) {
    int n = blockIdx.x * 4 + (threadIdx.x >> 6);
    int lane = threadIdx.x & 63;
    if (n >= N_NODES) return;
    int col = (lane >> 5) * 128 + (lane & 31) * 4;   // channel base in [0,256)
    float4 w4 = *(const float4*)(We + col);
    float4 a4 = *(const float4*)(att + col);
    ushort4 r4 = *(const ushort4*)(xr + (size_t)n * 256 + col);
    float rx = bf2f(r4.x), ry = bf2f(r4.y), rz = bf2f(r4.z), rw = bf2f(r4.w);
    int beg = offsets[n], end = offsets[n + 1];
    float mrun = -INFINITY, den = 0.f;
    float ax = 0.f, ay = 0.f, az = 0.f, aw = 0.f;
    for (int i = beg; i < end; i++) {
        int s = srcp[i];
        float w = ewp[i];
        ushort4 l4 = *(const ushort4*)(xl + (size_t)s * 256 + col);
        float lx = bf2f(l4.x), ly = bf2f(l4.y), lz = bf2f(l4.z), lw = bf2f(l4.w);
        float v, a = 0.f;
        v = lx + rx + w*w4.x; v = v > 0.f ? v : NEG_SLOPE*v; a += v*a4.x;
        v = ly + ry + w*w4.y; v = v > 0.f ? v : NEG_SLOPE*v; a += v*a4.y;
        v = lz + rz + w*w4.z; v = v > 0.f ? v : NEG_SLOPE*v; a += v*a4.z;
        v = lw + rw + w*w4.w; v = v > 0.f ? v : NEG_SLOPE*v; a += v*a4.w;
        #pragma unroll
        for (int mm = 1; mm <= 16; mm <<= 1) a += __shfl_xor(a, mm, 64);
        float nm = fmaxf(mrun, a);
        float sc = __expf(mrun - nm);   // first iter: exp(-inf)=0
        float p  = __expf(a - nm);
        den = den * sc + p;
        ax = ax * sc + p * lx;
        ay = ay * sc + p * ly;
        az = az * sc + p * lz;
        aw = aw * sc + p * lw;
        mrun = nm;
    }
    float inv = 1.f / (den + 1e-16f);
    if (CONCAT) {
        float4 b4 = *(const float4*)(bias + col);
        float4 o;
        o.x = ax*inv + b4.x; o.y = ay*inv + b4.y; o.z = az*inv + b4.z; o.w = aw*inv + b4.w;
        *(float4*)(out + (size_t)n * 256 + col) = o;
    } else {
        float ox = ax*inv, oy = ay*inv, oz = az*inv, ow = aw*inv;
        float px = __shfl_xor(ox, 32, 64);
        float py = __shfl_xor(oy, 32, 64);
        float pz = __shfl_xor(oz, 32, 64);
        float pw = __shfl_xor(ow, 32, 64);
        if (lane < 32) {
            float4 b4 = *(const float4*)(bias + lane * 4);
            float4 o;
            o.x = (ox + px)*0.5f + b4.x;
            o.y = (oy + py)*0.5f + b4.y;
            o.z = (oz + pz)*0.5f + b4.z;
            o.w = (ow + pw)*0.5f + b4.w;
            *(float4*)(out + (size_t)n * 128 + lane * 4) = o;
        }
    }
}

// ---------------- BN1 stats over [N,256] ----------------
__global__ void bn1_reduce(const float* __restrict__ x, float* __restrict__ sum,
                           float* __restrict__ sumsq) {
    int c = threadIdx.x;
    int r0 = blockIdx.x * 196;
    int r1 = r0 + 196; if (r1 > N_NODES) r1 = N_NODES;
    float s = 0.f, q = 0.f;
    for (int r = r0; r < r1; r++) {
        float v = x[r*256 + c];
        s += v; q += v*v;
    }
    atomicAdd(&sum[c], s);
    atomicAdd(&sumsq[c], q);
}

extern "C" void kernel_launch(void* const* d_in, const int* in_sizes, int n_in,
                              void* d_out, int out_size, void* d_ws, size_t ws_size,
                              hipStream_t stream) {
    const float* h          = (const float*)d_in[0];
    const int*   edge_index = (const int*)d_in[1];
    const int*   src = edge_index;
    const int*   dst = edge_index + N_EDGES;
    const float* ew   = (const float*)d_in[2];
    const float* bn0g = (const float*)d_in[3];
    const float* bn0b = (const float*)d_in[4];
    const float* bn1g = (const float*)d_in[5];
    const float* bn1b = (const float*)d_in[6];
    const float* c1_Wl = (const float*)d_in[7];
    const float* c1_bl = (const float*)d_in[8];
    const float* c1_Wr = (const float*)d_in[9];
    const float* c1_br = (const float*)d_in[10];
    const float* c1_We = (const float*)d_in[11];
    const float* c1_att = (const float*)d_in[12];
    const float* c1_bias = (const float*)d_in[13];
    const float* mu_Wl = (const float*)d_in[14];
    const float* mu_bl = (const float*)d_in[15];
    const float* mu_Wr = (const float*)d_in[16];
    const float* mu_br = (const float*)d_in[17];
    const float* mu_We = (const float*)d_in[18];
    const float* mu_att = (const float*)d_in[19];
    const float* mu_bias = (const float*)d_in[20];
    const float* ls_Wl = (const float*)d_in[21];
    const float* ls_bl = (const float*)d_in[22];
    const float* ls_Wr = (const float*)d_in[23];
    const float* ls_br = (const float*)d_in[24];
    const float* ls_We = (const float*)d_in[25];
    const float* ls_att = (const float*)d_in[26];
    const float* ls_bias = (const float*)d_in[27];

    float* out_mu = (float*)d_out;
    float* out_ls = (float*)d_out + (size_t)N_NODES * 128;

    // workspace carve-up (256B aligned blocks)
    char* ws = (char*)d_ws;
    size_t off = 0;
    auto alloc = [&](size_t bytes) -> void* {
        void* p = ws + off;
        off += (bytes + 255) / 256 * 256;
        return p;
    };
    float* x0      = (float*)alloc((size_t)N_NODES * 5 * 4);
    unsigned short* xl = (unsigned short*)alloc((size_t)N_NODES * 256 * 2);
    unsigned short* xr = (unsigned short*)alloc((size_t)N_NODES * 256 * 2);
    float* xB      = (float*)alloc((size_t)N_NODES * 256 * 4);
    float* bn0acc  = (float*)alloc(10 * 4);
    float* bn0ss   = (float*)alloc(10 * 4);
    float* bn1sum  = (float*)alloc(256 * 4);
    float* bn1sq   = (float*)alloc(256 * 4);
    int*   count   = (int*)alloc((size_t)N_NODES * 4);
    int*   offsets = (int*)alloc((size_t)(N_NODES + 1) * 4);
    int*   cursor  = (int*)alloc((size_t)N_NODES * 4);
    int*   srcp    = (int*)alloc((size_t)N_EDGES * 4);
    float* ewp     = (float*)alloc((size_t)N_EDGES * 4);
    int*   tileSum = (int*)alloc((size_t)SCAN_TILES * 4);
    int*   tilePre = (int*)alloc((size_t)SCAN_TILES * 4);
    unsigned short* Apack = (unsigned short*)alloc((size_t)RB_COUNT * 4096 * 2);  // 25.6 MB
    unsigned short* Bpack = (unsigned short*)alloc((size_t)2 * 131072 * 2);       // 512 KB

    hipMemsetAsync(count, 0, (size_t)N_NODES * 4, stream);
    hipMemsetAsync(bn0acc, 0, 10 * 4, stream);
    hipMemsetAsync(bn1sum, 0, 256 * 4, stream);
    hipMemsetAsync(bn1sq, 0, 256 * 4, stream);

    // BN0 (grid-parallel)
    bn0_reduce<<<128, 256, 0, stream>>>(h, bn0acc);
    bn0_finalize<<<1, 64, 0, stream>>>(bn0acc, bn0g, bn0b, bn0ss);
    bn0_apply<<<(N_NODES * 5 + 255) / 256, 256, 0, stream>>>(h, bn0ss, x0);

    // CSR by dst (shared by all 3 convs) — two-level parallel scan
    edge_count<<<(N_EDGES + 255) / 256, 256, 0, stream>>>(dst, count);
    local_scan<<<SCAN_TILES, 1024, 0, stream>>>(count, offsets, tileSum);
    tile_scan<<<1, 64, 0, stream>>>(tileSum, tilePre, offsets);
    add_prefix<<<SCAN_TILES, 1024, 0, stream>>>(offsets, tilePre, cursor);
    edge_scatter<<<(N_EDGES + 255) / 256, 256, 0, stream>>>(dst, src, ew, cursor, srcp, ewp);

    // pack mu/ls weights to bf16 fragment order
    pack_w<<<128, 256, 0, stream>>>(mu_Wl, mu_Wr, ls_Wl, ls_Wr, Bpack);

    // conv1 (concat)
    gemm_k5<<<N_NODES, 256, 0, stream>>>(x0, c1_Wl, c1_bl, c1_Wr, c1_br, xl, xr);
    agg_fused<1><<<N_NODES / 4 + 1, 256, 0, stream>>>(xl, xr, c1_We, c1_att, offsets,
                                                      srcp, ewp, c1_bias, xB);

    // BN1 stats; apply+ReLU fused into pack
    bn1_reduce<<<256, 256, 0, stream>>>(xB, bn1sum, bn1sq);
    pack_x_bn<<<6256, 256, 0, stream>>>(xB, bn1sum, bn1sq, bn1g, bn1b, Apack);

    // mu conv (head-mean)
    gemm_mfma<<<782, 512, 0, stream>>>(Apack, Bpack, mu_bl, mu_br, xl, xr);
    agg_fused<0><<<N_NODES / 4 + 1, 256, 0, stream>>>(xl, xr, mu_We, mu_att, offsets,
                                                      srcp, ewp, mu_bias, out_mu);

    // log_std conv (head-mean)
    gemm_mfma<<<782, 512, 0, stream>>>(Apack, Bpack + 131072, ls_bl, ls_br, xl, xr);
    agg_fused<0><<<N_NODES / 4 + 1, 256, 0, stream>>>(xl, xr, ls_We, ls_att, offsets,
                                                      srcp, ewp, ls_bias, out_ls);
}

// Round 6
// 469.354 us; speedup vs baseline: 2.9430x; 1.0895x over previous
//
#include <hip/hip_runtime.h>
#include <math.h>

#define N_NODES 50000
#define N_EDGES 300000
#define BN_EPS 1e-5f
#define NEG_SLOPE 0.2f

// 50000 rows pad to 3128 row-blocks of 16 (50048)
#define RB_COUNT 3128
#define SCAN_TILES 49   // 49*1024 = 50176 >= N_NODES

typedef short bf8v __attribute__((ext_vector_type(8)));
typedef float f4v __attribute__((ext_vector_type(4)));
typedef unsigned short u8v __attribute__((ext_vector_type(8)));

__device__ inline unsigned short f2bf(float f) {
    union { float f; unsigned u; } c; c.f = f;
    unsigned r = c.u + 0x7fffu + ((c.u >> 16) & 1u);
    return (unsigned short)(r >> 16);
}
__device__ inline float bf2f(unsigned short u) {
    union { unsigned u; float f; } c; c.u = ((unsigned)u) << 16;
    return c.f;
}

// async global->LDS DMA, 16B per lane; LDS dest = ldsbase + lane*16 (wave-uniform base)
__device__ inline void async_copy16(void* lds, const void* g) {
    __builtin_amdgcn_global_load_lds(
        (const __attribute__((address_space(1))) unsigned int*)g,
        (__attribute__((address_space(3))) unsigned int*)lds, 16, 0, 0);
}

// ---------------- BN0 (5 columns), grid-parallel ----------------
__global__ void bn0_reduce(const float* __restrict__ h, float* __restrict__ acc /*[10]*/) {
    __shared__ float lds[4][10];
    int tid = threadIdx.x;
    int lane = tid & 63, wave = tid >> 6;
    float ls[5] = {0,0,0,0,0}, lq[5] = {0,0,0,0,0};
    for (int r = blockIdx.x * 256 + tid; r < N_NODES; r += 128 * 256) {
        #pragma unroll
        for (int k = 0; k < 5; k++) {
            float v = h[r*5 + k];
            ls[k] += v; lq[k] += v*v;
        }
    }
    #pragma unroll
    for (int k = 0; k < 5; k++) {
        #pragma unroll
        for (int m = 1; m <= 32; m <<= 1) {
            ls[k] += __shfl_xor(ls[k], m, 64);
            lq[k] += __shfl_xor(lq[k], m, 64);
        }
    }
    if (lane == 0) {
        #pragma unroll
        for (int k = 0; k < 5; k++) { lds[wave][k] = ls[k]; lds[wave][5+k] = lq[k]; }
    }
    __syncthreads();
    if (tid < 10) {
        float s = lds[0][tid] + lds[1][tid] + lds[2][tid] + lds[3][tid];
        atomicAdd(&acc[tid], s);
    }
}

__global__ void bn0_finalize(const float* __restrict__ acc, const float* __restrict__ g,
                             const float* __restrict__ b, float* __restrict__ ss) {
    int tid = threadIdx.x;
    if (tid < 5) {
        float mean = acc[tid] * (1.f / N_NODES);
        float var  = acc[5 + tid] * (1.f / N_NODES) - mean*mean;
        float sc = g[tid] * rsqrtf(var + BN_EPS);
        ss[tid]     = sc;
        ss[5 + tid] = b[tid] - mean * sc;
    }
}

__global__ void bn0_apply(const float* __restrict__ h, const float* __restrict__ ss,
                          float* __restrict__ x0) {
    int i = blockIdx.x * blockDim.x + threadIdx.x;
    if (i < N_NODES * 5) {
        int k = i % 5;
        x0[i] = h[i] * ss[k] + ss[5 + k];
    }
}

// ---------------- CSR build by dst ----------------
__global__ void edge_count(const int* __restrict__ dst, int* __restrict__ count) {
    int e = blockIdx.x * blockDim.x + threadIdx.x;
    if (e < N_EDGES) atomicAdd(&count[dst[e]], 1);
}

// two-level scan: per-tile local exclusive scan + tile totals
__global__ void local_scan(const int* __restrict__ count, int* __restrict__ offsets,
                           int* __restrict__ tileSum) {
    __shared__ int lds[1024];
    int tid = threadIdx.x;
    int i = blockIdx.x * 1024 + tid;
    int v = (i < N_NODES) ? count[i] : 0;
    lds[tid] = v;
    __syncthreads();
    #pragma unroll
    for (int off = 1; off < 1024; off <<= 1) {
        int t = (tid >= off) ? lds[tid - off] : 0;
        __syncthreads();
        lds[tid] += t;
        __syncthreads();
    }
    if (i < N_NODES) offsets[i] = lds[tid] - v;   // local exclusive
    if (tid == 1023) tileSum[blockIdx.x] = lds[1023];
}

__global__ void tile_scan(const int* __restrict__ tileSum, int* __restrict__ tilePrefix,
                          int* __restrict__ offsets) {
    int lane = threadIdx.x;
    int v = (lane < SCAN_TILES) ? tileSum[lane] : 0;
    int inc = v;
    #pragma unroll
    for (int off = 1; off < 64; off <<= 1) {
        int t = __shfl_up(inc, off, 64);
        if (lane >= off) inc += t;
    }
    int excl = inc - v;
    if (lane < SCAN_TILES) tilePrefix[lane] = excl;
    if (lane == SCAN_TILES - 1) offsets[N_NODES] = inc;
}

__global__ void add_prefix(int* __restrict__ offsets, const int* __restrict__ tilePrefix,
                           int* __restrict__ cursor) {
    int i = blockIdx.x * 1024 + threadIdx.x;
    if (i < N_NODES) {
        int o = offsets[i] + tilePrefix[blockIdx.x];
        offsets[i] = o;
        cursor[i] = o;
    }
}

// scatter edge ids into CSR order; also materialize src and edge-weight in CSR order
__global__ void edge_scatter(const int* __restrict__ dst, const int* __restrict__ src,
                             const float* __restrict__ ew, int* __restrict__ cursor,
                             int* __restrict__ srcp, float* __restrict__ ewp) {
    int e = blockIdx.x * blockDim.x + threadIdx.x;
    if (e < N_EDGES) {
        int pos = atomicAdd(&cursor[dst[e]], 1);
        srcp[pos] = src[e];
        ewp[pos] = ew[e];
    }
}

// ---------------- conv1 linear (K=5), bf16 output ----------------
__global__ void gemm_k5(const float* __restrict__ x0,
                        const float* __restrict__ Wl, const float* __restrict__ bl,
                        const float* __restrict__ Wr, const float* __restrict__ br,
                        unsigned short* __restrict__ xl, unsigned short* __restrict__ xr) {
    int n = blockIdx.x;
    int c = threadIdx.x;
    float a0 = x0[n*5+0], a1 = x0[n*5+1], a2 = x0[n*5+2], a3 = x0[n*5+3], a4 = x0[n*5+4];
    float l = bl[c] + a0*Wl[c] + a1*Wl[256+c] + a2*Wl[512+c] + a3*Wl[768+c] + a4*Wl[1024+c];
    float r = br[c] + a0*Wr[c] + a1*Wr[256+c] + a2*Wr[512+c] + a3*Wr[768+c] + a4*Wr[1024+c];
    xl[n*256 + c] = f2bf(l);
    xr[n*256 + c] = f2bf(r);
}

// ---------------- pack X with fused BN1+ReLU (fp32 xB -> bf16 MFMA A-fragment order) ----
__global__ void pack_x_bn(const float* __restrict__ x,
                          const float* __restrict__ sum, const float* __restrict__ sumsq,
                          const float* __restrict__ g, const float* __restrict__ b,
                          unsigned short* __restrict__ ap) {
    int t = blockIdx.x * 256 + threadIdx.x;   // RB_COUNT*8*64 = 1601536 threads exact
    int lane = t & 63;
    int kc = (t >> 6) & 7;
    int rb = t >> 9;
    int row = rb * 16 + (lane & 15);
    int k0 = kc * 32 + (lane >> 4) * 8;
    union { unsigned short h[8]; uint4 u; } tmp;
    if (row < N_NODES) {
        const float* s = x + (size_t)row * 256 + k0;
        #pragma unroll
        for (int j = 0; j < 8; j++) {
            int c = k0 + j;
            float mean = sum[c] * (1.f / N_NODES);
            float var  = sumsq[c] * (1.f / N_NODES) - mean*mean;
            float sc = g[c] * rsqrtf(var + BN_EPS);
            float v = (s[j] - mean) * sc + b[c];
            v = v > 0.f ? v : 0.f;
            tmp.h[j] = f2bf(v);
        }
    } else {
        #pragma unroll
        for (int j = 0; j < 8; j++) tmp.h[j] = 0;
    }
    *reinterpret_cast<uint4*>(ap + (size_t)t * 8) = tmp.u;
}

// ---------------- pack W for both convs (fp32 -> bf16 MFMA B-fragment order) ----------------
__global__ void pack_w(const float* __restrict__ Wl0, const float* __restrict__ Wr0,
                       const float* __restrict__ Wl1, const float* __restrict__ Wr1,
                       unsigned short* __restrict__ bp) {
    int t = blockIdx.x * 256 + threadIdx.x;   // 2*8*32*64 = 32768 threads exact
    int lane = t & 63;
    int nt = (t >> 6) & 31;
    int kc = (t >> 11) & 7;
    int conv = t >> 14;
    int col = nt * 16 + (lane & 15);
    int k0 = kc * 32 + (lane >> 4) * 8;
    const float* W = conv ? (col < 256 ? Wl1 : Wr1) : (col < 256 ? Wl0 : Wr0);
    int c = col & 255;
    union { unsigned short h[8]; uint4 u; } tmp;
    #pragma unroll
    for (int j = 0; j < 8; j++) tmp.h[j] = f2bf(W[(size_t)(k0 + j) * 256 + c]);
    *reinterpret_cast<uint4*>(bp + (size_t)t * 8) = tmp.u;
}

// ---------------- big linear via MFMA, LDS-staged B (double-buffered), bf16 output -------
__global__ __launch_bounds__(512) void gemm_mfma(const unsigned short* __restrict__ ap,
        const unsigned short* __restrict__ bp,
        const float* __restrict__ bl, const float* __restrict__ br,
        unsigned short* __restrict__ xl, unsigned short* __restrict__ xr) {
    __shared__ unsigned short Bs[2][32][512];   // [buf][frag f=h*16+t][lane*8]
    int lane = threadIdx.x & 63;
    int wave = threadIdx.x >> 6;
    int h = wave & 1;
    int rb = blockIdx.x * 4 + (wave >> 1);

    const unsigned short* aptr = ap + (size_t)rb * 4096 + lane * 8;
    const unsigned short* bsrc = bp + lane * 8;

    // stage B[kc] into Bs[buf]: this wave's 4 frags (f = wave*4 + j; f -> offset f*512)
    auto stage = [&](int buf, int kc) {
        #pragma unroll
        for (int j = 0; j < 4; j++) {
            int f = wave * 4 + j;
            async_copy16(&Bs[buf][f][lane * 8], bsrc + (size_t)kc * 16384 + f * 512);
        }
    };
    stage(0, 0);

    // preload all A fragments (8 kc x 16B/lane = 32 VGPRs)
    bf8v a[8];
    #pragma unroll
    for (int kc = 0; kc < 8; kc++) a[kc] = *reinterpret_cast<const bf8v*>(aptr + kc * 512);

    f4v acc[16];
    #pragma unroll
    for (int t = 0; t < 16; t++) acc[t] = (f4v){0.f, 0.f, 0.f, 0.f};

    for (int kc = 0; kc < 8; kc++) {
        __syncthreads();                       // staging of buf kc&1 complete; prev buf free
        if (kc < 7) stage((kc + 1) & 1, kc + 1);
        const unsigned short* bb = &Bs[kc & 1][h * 16][lane * 8];
        #pragma unroll
        for (int t = 0; t < 16; t++) {
            bf8v b = *reinterpret_cast<const bf8v*>(bb + t * 512);
            acc[t] = __builtin_amdgcn_mfma_f32_16x16x32_bf16(a[kc], b, acc[t], 0, 0, 0);
        }
    }

    int c15 = lane & 15;
    int row0 = rb * 16 + (lane >> 4) * 4;
    unsigned short* outp = h ? xr : xl;
    const float* bias = h ? br : bl;
    #pragma unroll
    for (int t = 0; t < 16; t++) {
        int col = t * 16 + c15;
        float bv = bias[col];
        #pragma unroll
        for (int r = 0; r < 4; r++) {
            int row = row0 + r;
            if (row < N_NODES) outp[(size_t)row * 256 + col] = f2bf(acc[t][r] + bv);
        }
    }
}

// ---------------- fused GATv2 edge phase: alpha + online-softmax + aggregate ----------
// one wave per node, TWO edge streams per wave (lanes 0-31: even edges, 32-63: odd edges).
// Within a stream: 16 lanes per head, 8 channels per lane (16B gathers).
// Streams keep independent online-softmax state, merged at the end via shfl_xor 32.
template <int CONCAT>
__global__ void agg_fused(const unsigned short* __restrict__ xl,
                          const unsigned short* __restrict__ xr,
                          const float* __restrict__ We, const float* __restrict__ att,
                          const int* __restrict__ offsets, const int* __restrict__ srcp,
                          const float* __restrict__ ewp, const float* __restrict__ bias,
                          float* __restrict__ out) {
    int n = blockIdx.x * 4 + (threadIdx.x >> 6);
    int lane = threadIdx.x & 63;
    if (n >= N_NODES) return;
    int half = lane >> 5;                              // edge stream (even/odd)
    int sub  = lane & 31;
    int cb   = (sub >> 4) * 128 + (sub & 15) * 8;      // 8-channel base in [0,256)
    float wv[8], av[8], rv[8];
    *(float4*)&wv[0] = *(const float4*)(We + cb);
    *(float4*)&wv[4] = *(const float4*)(We + cb + 4);
    *(float4*)&av[0] = *(const float4*)(att + cb);
    *(float4*)&av[4] = *(const float4*)(att + cb + 4);
    u8v r8 = *(const u8v*)(xr + (size_t)n * 256 + cb);
    #pragma unroll
    for (int j = 0; j < 8; j++) rv[j] = bf2f(r8[j]);
    int beg = offsets[n], end = offsets[n + 1];
    float mrun = -1e30f, den = 0.f;
    float acc[8];
    #pragma unroll
    for (int j = 0; j < 8; j++) acc[j] = 0.f;

    int i = beg + half;
    int sN = 0; float wN = 0.f;
    u8v lN;
    #pragma unroll
    for (int j = 0; j < 8; j++) lN[j] = 0;
    if (i < end) {
        sN = srcp[i]; wN = ewp[i];
        lN = *(const u8v*)(xl + (size_t)sN * 256 + cb);
    }
    for (; i < end; i += 2) {
        u8v l8 = lN; float w = wN;
        int nx = i + 2;
        if (nx < end) {                              // distance-1 prefetch
            sN = srcp[nx]; wN = ewp[nx];
            lN = *(const u8v*)(xl + (size_t)sN * 256 + cb);
        }
        float lv[8];
        float a = 0.f;
        #pragma unroll
        for (int j = 0; j < 8; j++) {
            lv[j] = bf2f(l8[j]);
            float v = lv[j] + rv[j] + w * wv[j];
            v = fmaxf(v, NEG_SLOPE * v);             // leaky relu (slope<1)
            a += v * av[j];
        }
        a += __shfl_xor(a, 1, 64);
        a += __shfl_xor(a, 2, 64);
        a += __shfl_xor(a, 4, 64);
        a += __shfl_xor(a, 8, 64);                   // per-head alpha (16-lane groups)
        float nm = fmaxf(mrun, a);
        float scl = __expf(mrun - nm);
        float p = __expf(a - nm);
        den = den * scl + p;
        #pragma unroll
        for (int j = 0; j < 8; j++) acc[j] = acc[j] * scl + p * lv[j];
        mrun = nm;
    }
    // merge even/odd streams
    {
        float mo  = __shfl_xor(mrun, 32, 64);
        float dno = __shfl_xor(den, 32, 64);
        float nm = fmaxf(mrun, mo);
        float s0 = __expf(mrun - nm);
        float s1 = __expf(mo - nm);
        den = den * s0 + dno * s1;
        #pragma unroll
        for (int j = 0; j < 8; j++) {
            float ao = __shfl_xor(acc[j], 32, 64);
            acc[j] = acc[j] * s0 + ao * s1;
        }
    }
    float inv = 1.f / (den + 1e-16f);
    if (CONCAT) {
        if (lane < 32) {
            float o[8];
            #pragma unroll
            for (int j = 0; j < 8; j++) o[j] = acc[j] * inv + bias[cb + j];
            *(float4*)(out + (size_t)n * 256 + cb)     = *(float4*)&o[0];
            *(float4*)(out + (size_t)n * 256 + cb + 4) = *(float4*)&o[4];
        }
    } else {
        float o[8];
        #pragma unroll
        for (int j = 0; j < 8; j++) o[j] = acc[j] * inv;
        float po[8];
        #pragma unroll
        for (int j = 0; j < 8; j++) po[j] = __shfl_xor(o[j], 16, 64);  // other head, same ch
        if (lane < 16) {
            int c0 = (lane & 15) * 8;
            float r[8];
            #pragma unroll
            for (int j = 0; j < 8; j++) r[j] = (o[j] + po[j]) * 0.5f + bias[c0 + j];
            *(float4*)(out + (size_t)n * 128 + c0)     = *(float4*)&r[0];
            *(float4*)(out + (size_t)n * 128 + c0 + 4) = *(float4*)&r[4];
        }
    }
}

// ---------------- BN1 stats over [N,256] ----------------
__global__ void bn1_reduce(const float* __restrict__ x, float* __restrict__ sum,
                           float* __restrict__ sumsq) {
    int c = threadIdx.x;
    int r0 = blockIdx.x * 196;
    int r1 = r0 + 196; if (r1 > N_NODES) r1 = N_NODES;
    float s = 0.f, q = 0.f;
    for (int r = r0; r < r1; r++) {
        float v = x[r*256 + c];
        s += v; q += v*v;
    }
    atomicAdd(&sum[c], s);
    atomicAdd(&sumsq[c], q);
}

extern "C" void kernel_launch(void* const* d_in, const int* in_sizes, int n_in,
                              void* d_out, int out_size, void* d_ws, size_t ws_size,
                              hipStream_t stream) {
    const float* h          = (const float*)d_in[0];
    const int*   edge_index = (const int*)d_in[1];
    const int*   src = edge_index;
    const int*   dst = edge_index + N_EDGES;
    const float* ew   = (const float*)d_in[2];
    const float* bn0g = (const float*)d_in[3];
    const float* bn0b = (const float*)d_in[4];
    const float* bn1g = (const float*)d_in[5];
    const float* bn1b = (const float*)d_in[6];
    const float* c1_Wl = (const float*)d_in[7];
    const float* c1_bl = (const float*)d_in[8];
    const float* c1_Wr = (const float*)d_in[9];
    const float* c1_br = (const float*)d_in[10];
    const float* c1_We = (const float*)d_in[11];
    const float* c1_att = (const float*)d_in[12];
    const float* c1_bias = (const float*)d_in[13];
    const float* mu_Wl = (const float*)d_in[14];
    const float* mu_bl = (const float*)d_in[15];
    const float* mu_Wr = (const float*)d_in[16];
    const float* mu_br = (const float*)d_in[17];
    const float* mu_We = (const float*)d_in[18];
    const float* mu_att = (const float*)d_in[19];
    const float* mu_bias = (const float*)d_in[20];
    const float* ls_Wl = (const float*)d_in[21];
    const float* ls_bl = (const float*)d_in[22];
    const float* ls_Wr = (const float*)d_in[23];
    const float* ls_br = (const float*)d_in[24];
    const float* ls_We = (const float*)d_in[25];
    const float* ls_att = (const float*)d_in[26];
    const float* ls_bias = (const float*)d_in[27];

    float* out_mu = (float*)d_out;
    float* out_ls = (float*)d_out + (size_t)N_NODES * 128;

    // workspace carve-up (256B aligned blocks)
    char* ws = (char*)d_ws;
    size_t off = 0;
    auto alloc = [&](size_t bytes) -> void* {
        void* p = ws + off;
        off += (bytes + 255) / 256 * 256;
        return p;
    };
    float* x0      = (float*)alloc((size_t)N_NODES * 5 * 4);
    unsigned short* xl = (unsigned short*)alloc((size_t)N_NODES * 256 * 2);
    unsigned short* xr = (unsigned short*)alloc((size_t)N_NODES * 256 * 2);
    float* xB      = (float*)alloc((size_t)N_NODES * 256 * 4);
    float* bn0acc  = (float*)alloc(10 * 4);
    float* bn0ss   = (float*)alloc(10 * 4);
    float* bn1sum  = (float*)alloc(256 * 4);
    float* bn1sq   = (float*)alloc(256 * 4);
    int*   count   = (int*)alloc((size_t)N_NODES * 4);
    int*   offsets = (int*)alloc((size_t)(N_NODES + 1) * 4);
    int*   cursor  = (int*)alloc((size_t)N_NODES * 4);
    int*   srcp    = (int*)alloc((size_t)N_EDGES * 4);
    float* ewp     = (float*)alloc((size_t)N_EDGES * 4);
    int*   tileSum = (int*)alloc((size_t)SCAN_TILES * 4);
    int*   tilePre = (int*)alloc((size_t)SCAN_TILES * 4);
    unsigned short* Apack = (unsigned short*)alloc((size_t)RB_COUNT * 4096 * 2);  // 25.6 MB
    unsigned short* Bpack = (unsigned short*)alloc((size_t)2 * 131072 * 2);       // 512 KB

    hipMemsetAsync(count, 0, (size_t)N_NODES * 4, stream);
    hipMemsetAsync(bn0acc, 0, 10 * 4, stream);
    hipMemsetAsync(bn1sum, 0, 256 * 4, stream);
    hipMemsetAsync(bn1sq, 0, 256 * 4, stream);

    // BN0 (grid-parallel)
    bn0_reduce<<<128, 256, 0, stream>>>(h, bn0acc);
    bn0_finalize<<<1, 64, 0, stream>>>(bn0acc, bn0g, bn0b, bn0ss);
    bn0_apply<<<(N_NODES * 5 + 255) / 256, 256, 0, stream>>>(h, bn0ss, x0);

    // CSR by dst (shared by all 3 convs) — two-level parallel scan
    edge_count<<<(N_EDGES + 255) / 256, 256, 0, stream>>>(dst, count);
    local_scan<<<SCAN_TILES, 1024, 0, stream>>>(count, offsets, tileSum);
    tile_scan<<<1, 64, 0, stream>>>(tileSum, tilePre, offsets);
    add_prefix<<<SCAN_TILES, 1024, 0, stream>>>(offsets, tilePre, cursor);
    edge_scatter<<<(N_EDGES + 255) / 256, 256, 0, stream>>>(dst, src, ew, cursor, srcp, ewp);

    // pack mu/ls weights to bf16 fragment order
    pack_w<<<128, 256, 0, stream>>>(mu_Wl, mu_Wr, ls_Wl, ls_Wr, Bpack);

    // conv1 (concat)
    gemm_k5<<<N_NODES, 256, 0, stream>>>(x0, c1_Wl, c1_bl, c1_Wr, c1_br, xl, xr);
    agg_fused<1><<<N_NODES / 4 + 1, 256, 0, stream>>>(xl, xr, c1_We, c1_att, offsets,
                                                      srcp, ewp, c1_bias, xB);

    // BN1 stats; apply+ReLU fused into pack
    bn1_reduce<<<256, 256, 0, stream>>>(xB, bn1sum, bn1sq);
    pack_x_bn<<<6256, 256, 0, stream>>>(xB, bn1sum, bn1sq, bn1g, bn1b, Apack);

    // mu conv (head-mean)
    gemm_mfma<<<782, 512, 0, stream>>>(Apack, Bpack, mu_bl, mu_br, xl, xr);
    agg_fused<0><<<N_NODES / 4 + 1, 256, 0, stream>>>(xl, xr, mu_We, mu_att, offsets,
                                                      srcp, ewp, mu_bias, out_mu);

    // log_std conv (head-mean)
    gemm_mfma<<<782, 512, 0, stream>>>(Apack, Bpack + 131072, ls_bl, ls_br, xl, xr);
    agg_fused<0><<<N_NODES / 4 + 1, 256, 0, stream>>>(xl, xr, ls_We, ls_att, offsets,
                                                      srcp, ewp, ls_bias, out_ls);
}